// Round 1
// baseline (1219.264 us; speedup 1.0000x reference)
//
#include <hip/hip_runtime.h>

#define NRAD 20

// ---------------------------------------------------------------------------
// Detect edge_index storage: int32 (flag=1) vs int64 (flag=0).
// For int64 data, odd 32-bit words are hi-words of small nonneg values => 0.
// For int32 data, odd words are src node ids, ~never all zero across 64.
// ---------------------------------------------------------------------------
__global__ void detect_idx_kernel(const int* __restrict__ eidx, int* __restrict__ flag)
{
    int t = threadIdx.x;  // 64 threads, one wave
    unsigned long long m = __ballot(eidx[2 * t + 1] != 0);
    if (t == 0) flag[0] = (__popcll(m) > 8) ? 1 : 0;
}

// ---------------------------------------------------------------------------
// Node MLP: s = silu(node @ Ws^T + bs) @ Wphi^T + bphi   -> s_out (n_nodes,192)
// One wave per node; lane c owns output channels c, 64+c, 128+c.
// Weights staged transposed in LDS (padded) for conflict-free reads.
// Cross-lane broadcast of x / s1 via __shfl (constant lane index, unrolled).
// ---------------------------------------------------------------------------
__global__ __launch_bounds__(256, 2)
void node_mlp_kernel(const float* __restrict__ node,
                     const float* __restrict__ Ws,
                     const float* __restrict__ bs,
                     const float* __restrict__ Wphi,
                     const float* __restrict__ bphi,
                     float* __restrict__ s_out,
                     int n_nodes)
{
    __shared__ float WsT[64 * 65];     // WsT[k*65 + c] = Ws[c*64 + k]
    __shared__ float WphiT[64 * 193];  // WphiT[k*193 + j] = Wphi[j*64 + k]
    const int t = threadIdx.x;
    for (int i = t; i < 64 * 64; i += 256) {
        int c = i >> 6, k = i & 63;
        WsT[k * 65 + c] = Ws[i];
    }
    for (int i = t; i < 192 * 64; i += 256) {
        int j = i >> 6, k = i & 63;
        WphiT[k * 193 + j] = Wphi[i];
    }
    __syncthreads();

    const int lane = t & 63;
    const int wave = t >> 6;
    const int nwaves = (gridDim.x * blockDim.x) >> 6;
    const float bsc = bs[lane];
    const float bp0 = bphi[lane], bp1 = bphi[64 + lane], bp2 = bphi[128 + lane];

    for (int n = blockIdx.x * 4 + wave; n < n_nodes; n += nwaves) {
        float x = node[(size_t)n * 64 + lane];
        float acc = bsc;
#pragma unroll
        for (int k = 0; k < 64; k++) {
            acc += __shfl(x, k) * WsT[k * 65 + lane];
        }
        float s1 = acc / (1.0f + __expf(-acc));  // silu
        float a0 = bp0, a1 = bp1, a2 = bp2;
#pragma unroll
        for (int k = 0; k < 64; k++) {
            float sk = __shfl(s1, k);
            a0 += sk * WphiT[k * 193 + lane];
            a1 += sk * WphiT[k * 193 + 64 + lane];
            a2 += sk * WphiT[k * 193 + 128 + lane];
        }
        size_t ob = (size_t)n * 192;
        s_out[ob + lane] = a0;
        s_out[ob + 64 + lane] = a1;
        s_out[ob + 128 + lane] = a2;
    }
}

// ---------------------------------------------------------------------------
// Edge kernel: one wave per edge (grid-stride). Lane c owns channels
// c, 64+c, 128+c. Ww rows held in registers across the edge loop.
// Scatter via hardware f32 atomics.
// ---------------------------------------------------------------------------
__global__ __launch_bounds__(256)
void edge_kernel(const float* __restrict__ s,
                 const float* __restrict__ eq,
                 const float* __restrict__ rbf,
                 const float* __restrict__ env,
                 const float* __restrict__ rij,
                 const int* __restrict__ eidx,
                 const int* __restrict__ idx_flag,
                 const float* __restrict__ Ww,
                 const float* __restrict__ bw,
                 float* __restrict__ ds,
                 float* __restrict__ dv,
                 int n_edges)
{
    const int lane = threadIdx.x & 63;
    const int wglob = (blockIdx.x * blockDim.x + threadIdx.x) >> 6;
    const int nw = (gridDim.x * blockDim.x) >> 6;

    // Per-lane filter weight rows (held in registers across the loop).
    float ww0[NRAD], ww1[NRAD], ww2[NRAD];
#pragma unroll
    for (int k = 0; k < NRAD; k++) {
        ww0[k] = Ww[lane * NRAD + k];
        ww1[k] = Ww[(64 + lane) * NRAD + k];
        ww2[k] = Ww[(128 + lane) * NRAD + k];
    }
    const float bw0 = bw[lane], bw1 = bw[64 + lane], bw2 = bw[128 + lane];
    const int fmt32 = idx_flag[0];

    for (int e = wglob; e < n_edges; e += nw) {
        int dst, src;
        if (fmt32) {
            dst = eidx[2 * e];
            src = eidx[2 * e + 1];
        } else {
            const long long* e64 = (const long long*)eidx;
            dst = (int)e64[2 * e];
            src = (int)e64[2 * e + 1];
        }
        float ev = env[e];
        float r0 = rij[3 * e], r1 = rij[3 * e + 1], r2 = rij[3 * e + 2];

        float rb[NRAD];
#pragma unroll
        for (int k = 0; k < NRAD; k++) rb[k] = rbf[(size_t)e * NRAD + k];

        float w0 = bw0, w1 = bw1, w2 = bw2;
#pragma unroll
        for (int k = 0; k < NRAD; k++) {
            w0 += rb[k] * ww0[k];
            w1 += rb[k] * ww1[k];
            w2 += rb[k] * ww2[k];
        }
        w0 *= ev; w1 *= ev; w2 *= ev;

        size_t sb = (size_t)src * 192;
        float sw0 = s[sb + lane] * w0;          // -> ds
        float sw1 = s[sb + 64 + lane] * w1;     // -> multiplies vj
        float sw2 = s[sb + 128 + lane] * w2;    // -> multiplies r_ij

        float v0 = eq[sb + lane];
        float v1 = eq[sb + 64 + lane];
        float v2 = eq[sb + 128 + lane];

        unsafeAtomicAdd(&ds[(size_t)dst * 64 + lane], sw0);
        size_t db = (size_t)dst * 192;
        unsafeAtomicAdd(&dv[db + lane],       v0 * sw1 + r0 * sw2);
        unsafeAtomicAdd(&dv[db + 64 + lane],  v1 * sw1 + r1 * sw2);
        unsafeAtomicAdd(&dv[db + 128 + lane], v2 * sw1 + r2 * sw2);
    }
}

extern "C" void kernel_launch(void* const* d_in, const int* in_sizes, int n_in,
                              void* d_out, int out_size, void* d_ws, size_t ws_size,
                              hipStream_t stream)
{
    const float* node = (const float*)d_in[0];
    const float* eq   = (const float*)d_in[1];
    const float* rbf  = (const float*)d_in[2];
    const float* env  = (const float*)d_in[3];
    const float* rij  = (const float*)d_in[4];
    const int*   eidx = (const int*)d_in[5];
    const float* Ws   = (const float*)d_in[6];
    const float* bs   = (const float*)d_in[7];
    const float* Wphi = (const float*)d_in[8];
    const float* bphi = (const float*)d_in[9];
    const float* Ww   = (const float*)d_in[10];
    const float* bw   = (const float*)d_in[11];

    const int n_nodes = in_sizes[0] / 64;
    const int n_edges = in_sizes[3];  // envelope is (n_edges, 1)

    float* out = (float*)d_out;
    float* ds = out;
    float* dv = out + (size_t)n_nodes * 64;

    float* s_ws = (float*)d_ws;                       // n_nodes*192 floats
    int* idx_flag = (int*)((char*)d_ws + (size_t)n_nodes * 192 * sizeof(float));

    // Output accumulators start at zero (harness poisons with 0xAA).
    hipMemsetAsync(d_out, 0, (size_t)out_size * sizeof(float), stream);

    detect_idx_kernel<<<1, 64, 0, stream>>>(eidx, idx_flag);
    node_mlp_kernel<<<1024, 256, 0, stream>>>(node, Ws, bs, Wphi, bphi, s_ws, n_nodes);
    edge_kernel<<<4096, 256, 0, stream>>>(s_ws, eq, rbf, env, rij, eidx, idx_flag,
                                          Ww, bw, ds, dv, n_edges);
}

// Round 2
// 1138.737 us; speedup vs baseline: 1.0707x; 1.0707x over previous
//
#include <hip/hip_runtime.h>

#define NRAD 20
#define PADK 65

// ---------------------------------------------------------------------------
// Detect edge_index storage: int32 (flag=1) vs int64 (flag=0).
// ---------------------------------------------------------------------------
__global__ void detect_idx_kernel(const int* __restrict__ eidx, int* __restrict__ flag)
{
    int t = threadIdx.x;  // 64 threads, one wave
    unsigned long long m = __ballot(eidx[2 * t + 1] != 0);
    if (t == 0) flag[0] = (__popcll(m) > 8) ? 1 : 0;
}

// ---------------------------------------------------------------------------
// Transpose weights so the node-MLP can read rows via the scalar path.
// WsT[k*64+j] = Ws[j*64+k];  WphiT[k*192+j] = Wphi[j*64+k]
// ---------------------------------------------------------------------------
__global__ void trans_kernel(const float* __restrict__ Ws, const float* __restrict__ Wphi,
                             float* __restrict__ WsT, float* __restrict__ WphiT)
{
    int i0 = blockIdx.x * blockDim.x + threadIdx.x;
    int stride = gridDim.x * blockDim.x;
    for (int t = i0; t < 64 * 64; t += stride) {
        int j = t >> 6, k = t & 63;
        WsT[k * 64 + j] = Ws[t];
    }
    for (int t = i0; t < 192 * 64; t += stride) {
        int j = t >> 6, k = t & 63;
        WphiT[k * 192 + j] = Wphi[t];
    }
}

// ---------------------------------------------------------------------------
// CSR build: histogram of dst, exclusive scan, scatter edge ids.
// ---------------------------------------------------------------------------
__global__ void hist_kernel(const int* __restrict__ eidx, const int* __restrict__ flag,
                            int* __restrict__ counts, int n_edges)
{
    int fmt32 = flag[0];
    int i0 = blockIdx.x * blockDim.x + threadIdx.x;
    int stride = gridDim.x * blockDim.x;
    if (fmt32) {
        for (int e = i0; e < n_edges; e += stride) atomicAdd(&counts[eidx[2 * e]], 1);
    } else {
        const long long* e64 = (const long long*)eidx;
        for (int e = i0; e < n_edges; e += stride) atomicAdd(&counts[(int)e64[2 * e]], 1);
    }
}

__global__ __launch_bounds__(1024)
void scan_kernel(const int* __restrict__ cnt, int* __restrict__ offs, int n)
{
    __shared__ int wsum[16];
    __shared__ int csum;
    int tid = threadIdx.x, lane = tid & 63, w = tid >> 6;
    int carry = 0;
    for (int base = 0; base < n; base += 1024) {
        int i = base + tid;
        int v = (i < n) ? cnt[i] : 0;
        int sc = v;
#pragma unroll
        for (int d = 1; d < 64; d <<= 1) {
            int t = __shfl_up(sc, (unsigned)d, 64);
            if (lane >= d) sc += t;
        }
        if (lane == 63) wsum[w] = sc;
        __syncthreads();
        if (tid == 0) {
            int run = 0;
            for (int j = 0; j < 16; j++) { int t = wsum[j]; wsum[j] = run; run += t; }
            csum = run;
        }
        __syncthreads();
        int excl = carry + wsum[w] + (sc - v);
        if (i < n) offs[i] = excl;
        carry += csum;
        __syncthreads();
    }
    if (tid == 0) offs[n] = carry;
}

__global__ void scatter_kernel(const int* __restrict__ eidx, const int* __restrict__ flag,
                               const int* __restrict__ offs, int* __restrict__ cur,
                               int* __restrict__ sorted, int n_edges)
{
    int fmt32 = flag[0];
    int i0 = blockIdx.x * blockDim.x + threadIdx.x;
    int stride = gridDim.x * blockDim.x;
    const long long* e64 = (const long long*)eidx;
    for (int e = i0; e < n_edges; e += stride) {
        int dst = fmt32 ? eidx[2 * e] : (int)e64[2 * e];
        int pos = offs[dst] + atomicAdd(&cur[dst], 1);
        sorted[pos] = e;
    }
}

// ---------------------------------------------------------------------------
// Node MLP, scalar-weight form. One wave (block=64) per 64 nodes; lane = node.
// Weights stream through SGPRs (wave-uniform rows of WsT/WphiT); activations
// bounce through padded LDS once. Outputs stored PLANAR: s_planes[p][n][c].
// ---------------------------------------------------------------------------
__global__ __launch_bounds__(64)
void node_mlp2(const float* __restrict__ node,
               const float* __restrict__ bs_,
               const float* __restrict__ bphi_,
               const float* __restrict__ WsT,
               const float* __restrict__ WphiT,
               float* __restrict__ s_planes,
               size_t plane_n, int n_nodes)
{
    __shared__ float xbuf[64 * PADK];
    __shared__ float s1buf[64 * PADK];
    const int lane = threadIdx.x;
    const int nb = blockIdx.x * 64;

    // stage x: row m loaded coalesced (lane = channel), stored [node][k] padded
    for (int m = 0; m < 64; m++) {
        int nn = nb + m;
        float v = (nn < n_nodes) ? node[(size_t)nn * 64 + lane] : 0.f;
        xbuf[m * PADK + lane] = v;
    }
    __syncthreads();

    // layer 1: acc[j] = bs[j] + sum_k x[k] * WsT[k][j]
    float acc[64];
#pragma unroll
    for (int j = 0; j < 64; j++) acc[j] = bs_[j];
    for (int k = 0; k < 64; k++) {
        float xv = xbuf[lane * PADK + k];
        const float* wr = &WsT[k * 64];
#pragma unroll
        for (int j = 0; j < 64; j++) acc[j] += xv * wr[j];
    }
    // silu -> s1 LDS
#pragma unroll
    for (int j = 0; j < 64; j++) {
        float a = acc[j];
        float s = a / (1.f + __expf(-a));
        s1buf[lane * PADK + j] = s;
    }
    __syncthreads();

    // layer 2 in 3 passes of 64 outputs; results staged via xbuf for coalesced store
    for (int p = 0; p < 3; p++) {
        float a2[64];
#pragma unroll
        for (int j = 0; j < 64; j++) a2[j] = bphi_[p * 64 + j];
        for (int k = 0; k < 64; k++) {
            float sv = s1buf[lane * PADK + k];
            const float* wr = &WphiT[k * 192 + p * 64];
#pragma unroll
            for (int j = 0; j < 64; j++) a2[j] += sv * wr[j];
        }
        __syncthreads();  // xbuf free for reuse
#pragma unroll
        for (int j = 0; j < 64; j++) xbuf[lane * PADK + j] = a2[j];
        __syncthreads();
        float* plane = s_planes + (size_t)p * plane_n;
        for (int m = 0; m < 64; m++) {
            int nn = nb + m;
            if (nn < n_nodes) plane[(size_t)nn * 64 + lane] = xbuf[m * PADK + lane];
        }
        __syncthreads();
    }
}

// ---------------------------------------------------------------------------
// CSR accumulate: one wave per destination node, no atomics.
// ---------------------------------------------------------------------------
__global__ __launch_bounds__(256)
void accum_kernel(const float* __restrict__ s_planes, size_t plane_n,
                  const float* __restrict__ eq, const float* __restrict__ rbf,
                  const float* __restrict__ env, const float* __restrict__ rij,
                  const int* __restrict__ eidx, const int* __restrict__ flag,
                  const int* __restrict__ offs, const int* __restrict__ sorted,
                  const float* __restrict__ Ww, const float* __restrict__ bw,
                  float* __restrict__ ds, float* __restrict__ dv, int n_nodes)
{
    const int lane = threadIdx.x & 63;
    const int node = (blockIdx.x * blockDim.x + threadIdx.x) >> 6;
    if (node >= n_nodes) return;

    const float4* Ww4 = (const float4*)Ww;
    float4 w0q[5], w1q[5], w2q[5];
#pragma unroll
    for (int q = 0; q < 5; q++) {
        w0q[q] = Ww4[lane * 5 + q];
        w1q[q] = Ww4[(64 + lane) * 5 + q];
        w2q[q] = Ww4[(128 + lane) * 5 + q];
    }
    const float bw0 = bw[lane], bw1 = bw[64 + lane], bw2 = bw[128 + lane];
    const int fmt32 = flag[0];
    const long long* e64 = (const long long*)eidx;
    const float4* rbf4 = (const float4*)rbf;
    const float* s0p = s_planes;
    const float* s1p = s_planes + plane_n;
    const float* s2p = s_planes + 2 * plane_n;

    const int beg = offs[node], end = offs[node + 1];
    float a0 = 0.f, a1 = 0.f, a2 = 0.f, a3 = 0.f;

    for (int i = beg; i < end; i++) {
        int e = sorted[i];
        int src = fmt32 ? eidx[2 * e + 1] : (int)e64[2 * e + 1];
        float ev = env[e];
        float r0 = rij[3 * e], r1 = rij[3 * e + 1], r2 = rij[3 * e + 2];
        float4 rb[5];
#pragma unroll
        for (int q = 0; q < 5; q++) rb[q] = rbf4[(size_t)e * 5 + q];
        float w0 = bw0, w1 = bw1, w2 = bw2;
#pragma unroll
        for (int q = 0; q < 5; q++) {
            w0 += rb[q].x * w0q[q].x + rb[q].y * w0q[q].y + rb[q].z * w0q[q].z + rb[q].w * w0q[q].w;
            w1 += rb[q].x * w1q[q].x + rb[q].y * w1q[q].y + rb[q].z * w1q[q].z + rb[q].w * w1q[q].w;
            w2 += rb[q].x * w2q[q].x + rb[q].y * w2q[q].y + rb[q].z * w2q[q].z + rb[q].w * w2q[q].w;
        }
        w0 *= ev; w1 *= ev; w2 *= ev;

        size_t sb = (size_t)src * 64 + lane;
        float sw0 = s0p[sb] * w0;
        float sw1 = s1p[sb] * w1;
        float sw2 = s2p[sb] * w2;
        size_t qb = (size_t)src * 192 + lane;
        a0 += sw0;
        a1 += eq[qb] * sw1 + r0 * sw2;
        a2 += eq[qb + 64] * sw1 + r1 * sw2;
        a3 += eq[qb + 128] * sw1 + r2 * sw2;
    }
    ds[(size_t)node * 64 + lane] = a0;
    size_t db = (size_t)node * 192 + lane;
    dv[db] = a1;
    dv[db + 64] = a2;
    dv[db + 128] = a3;
}

// ===========================================================================
// Fallback path (round-1, proven to fit ws): row-major s + atomic scatter.
// ===========================================================================
__global__ __launch_bounds__(256, 2)
void node_mlp_kernel(const float* __restrict__ node,
                     const float* __restrict__ Ws,
                     const float* __restrict__ bs,
                     const float* __restrict__ Wphi,
                     const float* __restrict__ bphi,
                     float* __restrict__ s_out,
                     int n_nodes)
{
    __shared__ float WsT[64 * 65];
    __shared__ float WphiT[64 * 193];
    const int t = threadIdx.x;
    for (int i = t; i < 64 * 64; i += 256) {
        int c = i >> 6, k = i & 63;
        WsT[k * 65 + c] = Ws[i];
    }
    for (int i = t; i < 192 * 64; i += 256) {
        int j = i >> 6, k = i & 63;
        WphiT[k * 193 + j] = Wphi[i];
    }
    __syncthreads();

    const int lane = t & 63;
    const int wave = t >> 6;
    const int nwaves = (gridDim.x * blockDim.x) >> 6;
    const float bsc = bs[lane];
    const float bp0 = bphi[lane], bp1 = bphi[64 + lane], bp2 = bphi[128 + lane];

    for (int n = blockIdx.x * 4 + wave; n < n_nodes; n += nwaves) {
        float x = node[(size_t)n * 64 + lane];
        float acc = bsc;
#pragma unroll
        for (int k = 0; k < 64; k++) acc += __shfl(x, k) * WsT[k * 65 + lane];
        float s1 = acc / (1.0f + __expf(-acc));
        float a0 = bp0, a1 = bp1, a2 = bp2;
#pragma unroll
        for (int k = 0; k < 64; k++) {
            float sk = __shfl(s1, k);
            a0 += sk * WphiT[k * 193 + lane];
            a1 += sk * WphiT[k * 193 + 64 + lane];
            a2 += sk * WphiT[k * 193 + 128 + lane];
        }
        size_t ob = (size_t)n * 192;
        s_out[ob + lane] = a0;
        s_out[ob + 64 + lane] = a1;
        s_out[ob + 128 + lane] = a2;
    }
}

__global__ __launch_bounds__(256)
void edge_kernel(const float* __restrict__ s,
                 const float* __restrict__ eq,
                 const float* __restrict__ rbf,
                 const float* __restrict__ env,
                 const float* __restrict__ rij,
                 const int* __restrict__ eidx,
                 const int* __restrict__ idx_flag,
                 const float* __restrict__ Ww,
                 const float* __restrict__ bw,
                 float* __restrict__ ds,
                 float* __restrict__ dv,
                 int n_edges)
{
    const int lane = threadIdx.x & 63;
    const int wglob = (blockIdx.x * blockDim.x + threadIdx.x) >> 6;
    const int nw = (gridDim.x * blockDim.x) >> 6;

    float ww0[NRAD], ww1[NRAD], ww2[NRAD];
#pragma unroll
    for (int k = 0; k < NRAD; k++) {
        ww0[k] = Ww[lane * NRAD + k];
        ww1[k] = Ww[(64 + lane) * NRAD + k];
        ww2[k] = Ww[(128 + lane) * NRAD + k];
    }
    const float bw0 = bw[lane], bw1 = bw[64 + lane], bw2 = bw[128 + lane];
    const int fmt32 = idx_flag[0];

    for (int e = wglob; e < n_edges; e += nw) {
        int dst, src;
        if (fmt32) {
            dst = eidx[2 * e];
            src = eidx[2 * e + 1];
        } else {
            const long long* e64 = (const long long*)eidx;
            dst = (int)e64[2 * e];
            src = (int)e64[2 * e + 1];
        }
        float ev = env[e];
        float r0 = rij[3 * e], r1 = rij[3 * e + 1], r2 = rij[3 * e + 2];
        float rb[NRAD];
#pragma unroll
        for (int k = 0; k < NRAD; k++) rb[k] = rbf[(size_t)e * NRAD + k];
        float w0 = bw0, w1 = bw1, w2 = bw2;
#pragma unroll
        for (int k = 0; k < NRAD; k++) {
            w0 += rb[k] * ww0[k];
            w1 += rb[k] * ww1[k];
            w2 += rb[k] * ww2[k];
        }
        w0 *= ev; w1 *= ev; w2 *= ev;

        size_t sb = (size_t)src * 192;
        float sw0 = s[sb + lane] * w0;
        float sw1 = s[sb + 64 + lane] * w1;
        float sw2 = s[sb + 128 + lane] * w2;
        float v0 = eq[sb + lane];
        float v1 = eq[sb + 64 + lane];
        float v2 = eq[sb + 128 + lane];

        unsafeAtomicAdd(&ds[(size_t)dst * 64 + lane], sw0);
        size_t db = (size_t)dst * 192;
        unsafeAtomicAdd(&dv[db + lane],       v0 * sw1 + r0 * sw2);
        unsafeAtomicAdd(&dv[db + 64 + lane],  v1 * sw1 + r1 * sw2);
        unsafeAtomicAdd(&dv[db + 128 + lane], v2 * sw1 + r2 * sw2);
    }
}

extern "C" void kernel_launch(void* const* d_in, const int* in_sizes, int n_in,
                              void* d_out, int out_size, void* d_ws, size_t ws_size,
                              hipStream_t stream)
{
    const float* node = (const float*)d_in[0];
    const float* eq   = (const float*)d_in[1];
    const float* rbf  = (const float*)d_in[2];
    const float* env  = (const float*)d_in[3];
    const float* rij  = (const float*)d_in[4];
    const int*   eidx = (const int*)d_in[5];
    const float* Ws   = (const float*)d_in[6];
    const float* bs   = (const float*)d_in[7];
    const float* Wphi = (const float*)d_in[8];
    const float* bphi = (const float*)d_in[9];
    const float* Ww   = (const float*)d_in[10];
    const float* bw   = (const float*)d_in[11];

    const int n_nodes = in_sizes[0] / 64;
    const int n_edges = in_sizes[3];

    float* out = (float*)d_out;
    float* ds = out;
    float* dv = out + (size_t)n_nodes * 64;

    // ws layout (256B aligned slots)
    size_t off = 0;
    auto alloc = [&](size_t bytes) { size_t o = off; off = (off + bytes + 255) & ~(size_t)255; return o; };
    const size_t plane_n = (size_t)n_nodes * 64;
    size_t o_planes = alloc(3 * plane_n * sizeof(float));
    size_t o_wst    = alloc(64 * 64 * sizeof(float));
    size_t o_wphit  = alloc(64 * 192 * sizeof(float));
    size_t o_cnt    = alloc(2 * (size_t)n_nodes * sizeof(int));   // counts + cur adjacent
    size_t o_offs   = alloc(((size_t)n_nodes + 1) * sizeof(int));
    size_t o_sorted = alloc((size_t)n_edges * sizeof(int));
    size_t o_flag   = alloc(16);
    size_t needed = off;

    char* ws = (char*)d_ws;

    if (ws_size >= needed) {
        float* s_planes = (float*)(ws + o_planes);
        float* WsT      = (float*)(ws + o_wst);
        float* WphiT    = (float*)(ws + o_wphit);
        int*   counts   = (int*)(ws + o_cnt);
        int*   cur      = counts + n_nodes;
        int*   offs     = (int*)(ws + o_offs);
        int*   sorted   = (int*)(ws + o_sorted);
        int*   flag     = (int*)(ws + o_flag);

        hipMemsetAsync(counts, 0, 2 * (size_t)n_nodes * sizeof(int), stream);
        detect_idx_kernel<<<1, 64, 0, stream>>>(eidx, flag);
        trans_kernel<<<64, 256, 0, stream>>>(Ws, Wphi, WsT, WphiT);
        hist_kernel<<<1024, 256, 0, stream>>>(eidx, flag, counts, n_edges);
        scan_kernel<<<1, 1024, 0, stream>>>(counts, offs, n_nodes);
        scatter_kernel<<<1024, 256, 0, stream>>>(eidx, flag, offs, cur, sorted, n_edges);
        node_mlp2<<<(n_nodes + 63) / 64, 64, 0, stream>>>(node, bs, bphi, WsT, WphiT,
                                                          s_planes, plane_n, n_nodes);
        accum_kernel<<<(n_nodes + 3) / 4, 256, 0, stream>>>(
            s_planes, plane_n, eq, rbf, env, rij, eidx, flag, offs, sorted,
            Ww, bw, ds, dv, n_nodes);
    } else {
        // round-1 fallback (proven ws footprint: 38.4 MB + 4)
        float* s_ws = (float*)d_ws;
        int* idx_flag = (int*)(ws + (size_t)n_nodes * 192 * sizeof(float));
        hipMemsetAsync(d_out, 0, (size_t)out_size * sizeof(float), stream);
        detect_idx_kernel<<<1, 64, 0, stream>>>(eidx, idx_flag);
        node_mlp_kernel<<<1024, 256, 0, stream>>>(node, Ws, bs, Wphi, bphi, s_ws, n_nodes);
        edge_kernel<<<4096, 256, 0, stream>>>(s_ws, eq, rbf, env, rij, eidx, idx_flag,
                                              Ww, bw, ds, dv, n_edges);
    }
}

// Round 3
// 787.075 us; speedup vs baseline: 1.5491x; 1.4468x over previous
//
#include <hip/hip_runtime.h>

#define NRAD 20
#define PADK 65

// ---------------------------------------------------------------------------
// Detect edge_index storage: int32 (flag=1) vs int64 (flag=0).
// ---------------------------------------------------------------------------
__global__ void detect_idx_kernel(const int* __restrict__ eidx, int* __restrict__ flag)
{
    int t = threadIdx.x;  // 64 threads, one wave
    unsigned long long m = __ballot(eidx[2 * t + 1] != 0);
    if (t == 0) flag[0] = (__popcll(m) > 8) ? 1 : 0;
}

// ---------------------------------------------------------------------------
// Transpose weights for the scalar-path node MLP.
// ---------------------------------------------------------------------------
__global__ void trans_kernel(const float* __restrict__ Ws, const float* __restrict__ Wphi,
                             float* __restrict__ WsT, float* __restrict__ WphiT)
{
    int i0 = blockIdx.x * blockDim.x + threadIdx.x;
    int stride = gridDim.x * blockDim.x;
    for (int t = i0; t < 64 * 64; t += stride) {
        int j = t >> 6, k = t & 63;
        WsT[k * 64 + j] = Ws[t];
    }
    for (int t = i0; t < 192 * 64; t += stride) {
        int j = t >> 6, k = t & 63;
        WphiT[k * 192 + j] = Wphi[t];
    }
}

// ---------------------------------------------------------------------------
// CSR build: histogram, 3-stage scan, scatter.
// ---------------------------------------------------------------------------
__global__ void hist_kernel(const int* __restrict__ eidx, const int* __restrict__ flag,
                            int* __restrict__ counts, int n_edges)
{
    int fmt32 = flag[0];
    int i0 = blockIdx.x * blockDim.x + threadIdx.x;
    int stride = gridDim.x * blockDim.x;
    if (fmt32) {
        for (int e = i0; e < n_edges; e += stride) atomicAdd(&counts[eidx[2 * e]], 1);
    } else {
        const long long* e64 = (const long long*)eidx;
        for (int e = i0; e < n_edges; e += stride) atomicAdd(&counts[(int)e64[2 * e]], 1);
    }
}

__global__ __launch_bounds__(256)
void scan1_kernel(const int* __restrict__ cnt, int* __restrict__ bsum, int n, int ch)
{
    __shared__ int red[4];
    int b = blockIdx.x, t = threadIdx.x;
    int end = min(n, (b + 1) * ch);
    int v = 0;
    for (int i = b * ch + t; i < end; i += 256) v += cnt[i];
#pragma unroll
    for (int d = 1; d < 64; d <<= 1) v += __shfl_xor(v, d, 64);
    if ((t & 63) == 0) red[t >> 6] = v;
    __syncthreads();
    if (t == 0) bsum[b] = red[0] + red[1] + red[2] + red[3];
}

__global__ __launch_bounds__(256)
void scan2_kernel(const int* __restrict__ bsum, int* __restrict__ bscan,
                  int* __restrict__ offs, int nb, int n)
{
    __shared__ int wsum[4];
    int t = threadIdx.x, lane = t & 63, w = t >> 6;
    int v = (t < nb) ? bsum[t] : 0;
    int sc = v;
#pragma unroll
    for (int d = 1; d < 64; d <<= 1) {
        int u = __shfl_up(sc, (unsigned)d, 64);
        if (lane >= d) sc += u;
    }
    if (lane == 63) wsum[w] = sc;
    __syncthreads();
    int add = 0;
    for (int j = 0; j < w; j++) add += wsum[j];
    int incl = sc + add;
    if (t < nb) bscan[t] = incl - v;
    if (t == nb - 1) offs[n] = incl;  // grand total
}

__global__ __launch_bounds__(256)
void scan3_kernel(const int* __restrict__ cnt, const int* __restrict__ bscan,
                  int* __restrict__ offs, int n, int ch)
{
    __shared__ int wsum[4];
    __shared__ int btot;
    int b = blockIdx.x, t = threadIdx.x, lane = t & 63, w = t >> 6;
    int end = min(n, (b + 1) * ch);
    int carry = bscan[b];
    for (int base = b * ch; base < end; base += 256) {
        int i = base + t;
        int v = (i < end) ? cnt[i] : 0;
        int sc = v;
#pragma unroll
        for (int d = 1; d < 64; d <<= 1) {
            int u = __shfl_up(sc, (unsigned)d, 64);
            if (lane >= d) sc += u;
        }
        if (lane == 63) wsum[w] = sc;
        __syncthreads();
        int add = 0;
        for (int j = 0; j < w; j++) add += wsum[j];
        if (t == 255) btot = sc + add;
        int excl = carry + (sc + add - v);
        if (i < end) offs[i] = excl;
        __syncthreads();
        carry += btot;
    }
}

__global__ void scatter_kernel(const int* __restrict__ eidx, const int* __restrict__ flag,
                               int* __restrict__ cur, int* __restrict__ sorted, int n_edges)
{
    int fmt32 = flag[0];
    int i0 = blockIdx.x * blockDim.x + threadIdx.x;
    int stride = gridDim.x * blockDim.x;
    const long long* e64 = (const long long*)eidx;
    for (int e = i0; e < n_edges; e += stride) {
        int dst = fmt32 ? eidx[2 * e] : (int)e64[2 * e];
        int pos = atomicAdd(&cur[dst], 1);
        sorted[pos] = e;
    }
}

// ---------------------------------------------------------------------------
// Node MLP, scalar-weight form (unchanged from round 2 — verified).
// ---------------------------------------------------------------------------
__global__ __launch_bounds__(64)
void node_mlp2(const float* __restrict__ node,
               const float* __restrict__ bs_,
               const float* __restrict__ bphi_,
               const float* __restrict__ WsT,
               const float* __restrict__ WphiT,
               float* __restrict__ s_planes,
               size_t plane_n, int n_nodes)
{
    __shared__ float xbuf[64 * PADK];
    __shared__ float s1buf[64 * PADK];
    const int lane = threadIdx.x;
    const int nb = blockIdx.x * 64;

    for (int m = 0; m < 64; m++) {
        int nn = nb + m;
        float v = (nn < n_nodes) ? node[(size_t)nn * 64 + lane] : 0.f;
        xbuf[m * PADK + lane] = v;
    }
    __syncthreads();

    float acc[64];
#pragma unroll
    for (int j = 0; j < 64; j++) acc[j] = bs_[j];
    for (int k = 0; k < 64; k++) {
        float xv = xbuf[lane * PADK + k];
        const float* wr = &WsT[k * 64];
#pragma unroll
        for (int j = 0; j < 64; j++) acc[j] += xv * wr[j];
    }
#pragma unroll
    for (int j = 0; j < 64; j++) {
        float a = acc[j];
        s1buf[lane * PADK + j] = a / (1.f + __expf(-a));
    }
    __syncthreads();

    for (int p = 0; p < 3; p++) {
        float a2[64];
#pragma unroll
        for (int j = 0; j < 64; j++) a2[j] = bphi_[p * 64 + j];
        for (int k = 0; k < 64; k++) {
            float sv = s1buf[lane * PADK + k];
            const float* wr = &WphiT[k * 192 + p * 64];
#pragma unroll
            for (int j = 0; j < 64; j++) a2[j] += sv * wr[j];
        }
        __syncthreads();
#pragma unroll
        for (int j = 0; j < 64; j++) xbuf[lane * PADK + j] = a2[j];
        __syncthreads();
        float* plane = s_planes + (size_t)p * plane_n;
        for (int m = 0; m < 64; m++) {
            int nn = nb + m;
            if (nn < n_nodes) plane[(size_t)nn * 64 + lane] = xbuf[m * PADK + lane];
        }
        __syncthreads();
    }
}

// ---------------------------------------------------------------------------
// Tiled accumulate: each wave owns 64 contiguous sorted edges.
// Phase 1 (lane=edge): fetch metadata with independent parallel loads -> LDS.
// Phase 2 (lane=channel): loop staged edges, gather s/eq, accumulate in regs,
// flush with f32 atomics only at dst boundaries.
// ---------------------------------------------------------------------------
__global__ __launch_bounds__(256)
void accum2_kernel(const float* __restrict__ s_planes, size_t plane_n,
                   const float* __restrict__ eq, const float* __restrict__ rbf,
                   const float* __restrict__ env, const float* __restrict__ rij,
                   const int* __restrict__ eidx, const int* __restrict__ flag,
                   const int* __restrict__ sorted,
                   const float* __restrict__ Ww, const float* __restrict__ bw,
                   float* __restrict__ ds, float* __restrict__ dv,
                   int n_edges)
{
    __shared__ int    sh_dst[4 * 64];
    __shared__ int    sh_src[4 * 64];
    __shared__ float  sh_env[4 * 64];
    __shared__ float  sh_r[4 * 3 * 64];          // [w][comp][edge]
    __shared__ float4 sh_rbf[4 * 64 * 5];        // [w][edge][q]

    const int lane = threadIdx.x & 63;
    const int w = threadIdx.x >> 6;
    const int tile = blockIdx.x * 4 + w;
    const int base = tile * 64;
    const int nvalid = min(64, n_edges - base);
    const int woff = w * 64;

    // ---- Phase 1: lane = edge ----
    if (lane < nvalid) {
        int e = sorted[base + lane];
        int d_, s_;
        if (flag[0]) {
            const int2* p2 = (const int2*)eidx;
            int2 v = p2[e];
            d_ = v.x; s_ = v.y;
        } else {
            const longlong2* p2 = (const longlong2*)eidx;
            longlong2 v = p2[e];
            d_ = (int)v.x; s_ = (int)v.y;
        }
        sh_dst[woff + lane] = d_;
        sh_src[woff + lane] = s_;
        sh_env[woff + lane] = env[e];
        sh_r[w * 192 + lane]       = rij[3 * e];
        sh_r[w * 192 + 64 + lane]  = rij[3 * e + 1];
        sh_r[w * 192 + 128 + lane] = rij[3 * e + 2];
        const float4* rbf4 = (const float4*)rbf;
#pragma unroll
        for (int q = 0; q < 5; q++) sh_rbf[(woff + lane) * 5 + q] = rbf4[(size_t)e * 5 + q];
    }
    __syncthreads();

    if (nvalid <= 0) return;

    // per-lane filter weights in registers
    const float4* Ww4 = (const float4*)Ww;
    float4 w0q[5], w1q[5], w2q[5];
#pragma unroll
    for (int q = 0; q < 5; q++) {
        w0q[q] = Ww4[lane * 5 + q];
        w1q[q] = Ww4[(64 + lane) * 5 + q];
        w2q[q] = Ww4[(128 + lane) * 5 + q];
    }
    const float bw0 = bw[lane], bw1 = bw[64 + lane], bw2 = bw[128 + lane];

    const float* s0p = s_planes;
    const float* s1p = s_planes + plane_n;
    const float* s2p = s_planes + 2 * plane_n;

    float a0 = 0.f, a1 = 0.f, a2 = 0.f, a3 = 0.f;
    int cur = sh_dst[woff];

    // ---- Phase 2: lane = channel ----
    for (int j = 0; j < nvalid; j++) {
        int src = sh_src[woff + j];
        float ev = sh_env[woff + j];
        float r0 = sh_r[w * 192 + j];
        float r1 = sh_r[w * 192 + 64 + j];
        float r2 = sh_r[w * 192 + 128 + j];

        float w0 = bw0, w1 = bw1, w2 = bw2;
#pragma unroll
        for (int q = 0; q < 5; q++) {
            float4 rb = sh_rbf[(woff + j) * 5 + q];
            w0 += rb.x * w0q[q].x + rb.y * w0q[q].y + rb.z * w0q[q].z + rb.w * w0q[q].w;
            w1 += rb.x * w1q[q].x + rb.y * w1q[q].y + rb.z * w1q[q].z + rb.w * w1q[q].w;
            w2 += rb.x * w2q[q].x + rb.y * w2q[q].y + rb.z * w2q[q].z + rb.w * w2q[q].w;
        }
        w0 *= ev; w1 *= ev; w2 *= ev;

        size_t sb = (size_t)src * 64 + lane;
        float sw0 = s0p[sb] * w0;
        float sw1 = s1p[sb] * w1;
        float sw2 = s2p[sb] * w2;
        size_t qb = (size_t)src * 192 + lane;
        a0 += sw0;
        a1 += eq[qb] * sw1 + r0 * sw2;
        a2 += eq[qb + 64] * sw1 + r1 * sw2;
        a3 += eq[qb + 128] * sw1 + r2 * sw2;

        int nd = (j + 1 < nvalid) ? sh_dst[woff + j + 1] : -2;
        if (nd != cur) {
            unsafeAtomicAdd(&ds[(size_t)cur * 64 + lane], a0);
            size_t db = (size_t)cur * 192 + lane;
            unsafeAtomicAdd(&dv[db], a1);
            unsafeAtomicAdd(&dv[db + 64], a2);
            unsafeAtomicAdd(&dv[db + 128], a3);
            a0 = a1 = a2 = a3 = 0.f;
            cur = nd;
        }
    }
}

// ===========================================================================
// Fallback path (round-1, proven): row-major s + atomic scatter.
// ===========================================================================
__global__ __launch_bounds__(256, 2)
void node_mlp_kernel(const float* __restrict__ node,
                     const float* __restrict__ Ws,
                     const float* __restrict__ bs,
                     const float* __restrict__ Wphi,
                     const float* __restrict__ bphi,
                     float* __restrict__ s_out,
                     int n_nodes)
{
    __shared__ float WsT[64 * 65];
    __shared__ float WphiT[64 * 193];
    const int t = threadIdx.x;
    for (int i = t; i < 64 * 64; i += 256) {
        int c = i >> 6, k = i & 63;
        WsT[k * 65 + c] = Ws[i];
    }
    for (int i = t; i < 192 * 64; i += 256) {
        int j = i >> 6, k = i & 63;
        WphiT[k * 193 + j] = Wphi[i];
    }
    __syncthreads();

    const int lane = t & 63;
    const int wave = t >> 6;
    const int nwaves = (gridDim.x * blockDim.x) >> 6;
    const float bsc = bs[lane];
    const float bp0 = bphi[lane], bp1 = bphi[64 + lane], bp2 = bphi[128 + lane];

    for (int n = blockIdx.x * 4 + wave; n < n_nodes; n += nwaves) {
        float x = node[(size_t)n * 64 + lane];
        float acc = bsc;
#pragma unroll
        for (int k = 0; k < 64; k++) acc += __shfl(x, k) * WsT[k * 65 + lane];
        float s1 = acc / (1.0f + __expf(-acc));
        float a0 = bp0, a1 = bp1, a2 = bp2;
#pragma unroll
        for (int k = 0; k < 64; k++) {
            float sk = __shfl(s1, k);
            a0 += sk * WphiT[k * 193 + lane];
            a1 += sk * WphiT[k * 193 + 64 + lane];
            a2 += sk * WphiT[k * 193 + 128 + lane];
        }
        size_t ob = (size_t)n * 192;
        s_out[ob + lane] = a0;
        s_out[ob + 64 + lane] = a1;
        s_out[ob + 128 + lane] = a2;
    }
}

__global__ __launch_bounds__(256)
void edge_kernel(const float* __restrict__ s,
                 const float* __restrict__ eq,
                 const float* __restrict__ rbf,
                 const float* __restrict__ env,
                 const float* __restrict__ rij,
                 const int* __restrict__ eidx,
                 const int* __restrict__ idx_flag,
                 const float* __restrict__ Ww,
                 const float* __restrict__ bw,
                 float* __restrict__ ds,
                 float* __restrict__ dv,
                 int n_edges)
{
    const int lane = threadIdx.x & 63;
    const int wglob = (blockIdx.x * blockDim.x + threadIdx.x) >> 6;
    const int nw = (gridDim.x * blockDim.x) >> 6;

    float ww0[NRAD], ww1[NRAD], ww2[NRAD];
#pragma unroll
    for (int k = 0; k < NRAD; k++) {
        ww0[k] = Ww[lane * NRAD + k];
        ww1[k] = Ww[(64 + lane) * NRAD + k];
        ww2[k] = Ww[(128 + lane) * NRAD + k];
    }
    const float bw0 = bw[lane], bw1 = bw[64 + lane], bw2 = bw[128 + lane];
    const int fmt32 = idx_flag[0];

    for (int e = wglob; e < n_edges; e += nw) {
        int dst, src;
        if (fmt32) {
            dst = eidx[2 * e];
            src = eidx[2 * e + 1];
        } else {
            const long long* e64 = (const long long*)eidx;
            dst = (int)e64[2 * e];
            src = (int)e64[2 * e + 1];
        }
        float ev = env[e];
        float r0 = rij[3 * e], r1 = rij[3 * e + 1], r2 = rij[3 * e + 2];
        float rb[NRAD];
#pragma unroll
        for (int k = 0; k < NRAD; k++) rb[k] = rbf[(size_t)e * NRAD + k];
        float w0 = bw0, w1 = bw1, w2 = bw2;
#pragma unroll
        for (int k = 0; k < NRAD; k++) {
            w0 += rb[k] * ww0[k];
            w1 += rb[k] * ww1[k];
            w2 += rb[k] * ww2[k];
        }
        w0 *= ev; w1 *= ev; w2 *= ev;

        size_t sb = (size_t)src * 192;
        float sw0 = s[sb + lane] * w0;
        float sw1 = s[sb + 64 + lane] * w1;
        float sw2 = s[sb + 128 + lane] * w2;
        float v0 = eq[sb + lane];
        float v1 = eq[sb + 64 + lane];
        float v2 = eq[sb + 128 + lane];

        unsafeAtomicAdd(&ds[(size_t)dst * 64 + lane], sw0);
        size_t db = (size_t)dst * 192;
        unsafeAtomicAdd(&dv[db + lane],       v0 * sw1 + r0 * sw2);
        unsafeAtomicAdd(&dv[db + 64 + lane],  v1 * sw1 + r1 * sw2);
        unsafeAtomicAdd(&dv[db + 128 + lane], v2 * sw1 + r2 * sw2);
    }
}

extern "C" void kernel_launch(void* const* d_in, const int* in_sizes, int n_in,
                              void* d_out, int out_size, void* d_ws, size_t ws_size,
                              hipStream_t stream)
{
    const float* node = (const float*)d_in[0];
    const float* eq   = (const float*)d_in[1];
    const float* rbf  = (const float*)d_in[2];
    const float* env  = (const float*)d_in[3];
    const float* rij  = (const float*)d_in[4];
    const int*   eidx = (const int*)d_in[5];
    const float* Ws   = (const float*)d_in[6];
    const float* bs   = (const float*)d_in[7];
    const float* Wphi = (const float*)d_in[8];
    const float* bphi = (const float*)d_in[9];
    const float* Ww   = (const float*)d_in[10];
    const float* bw   = (const float*)d_in[11];

    const int n_nodes = in_sizes[0] / 64;
    const int n_edges = in_sizes[3];

    float* out = (float*)d_out;
    float* ds = out;
    float* dv = out + (size_t)n_nodes * 64;

    // ws layout (256B aligned slots)
    size_t off = 0;
    auto alloc = [&](size_t bytes) { size_t o = off; off = (off + bytes + 255) & ~(size_t)255; return o; };
    const size_t plane_n = (size_t)n_nodes * 64;
    size_t o_planes = alloc(3 * plane_n * sizeof(float));
    size_t o_wst    = alloc(64 * 64 * sizeof(float));
    size_t o_wphit  = alloc(64 * 192 * sizeof(float));
    size_t o_cnt    = alloc(2 * (size_t)n_nodes * sizeof(int));   // counts + cur
    size_t o_offs   = alloc(((size_t)n_nodes + 1) * sizeof(int));
    size_t o_sorted = alloc((size_t)n_edges * sizeof(int));
    size_t o_bsum   = alloc(512 * sizeof(int));                   // bsum + bscan
    size_t o_flag   = alloc(16);
    size_t needed = off;

    char* ws = (char*)d_ws;

    if (ws_size >= needed) {
        float* s_planes = (float*)(ws + o_planes);
        float* WsT      = (float*)(ws + o_wst);
        float* WphiT    = (float*)(ws + o_wphit);
        int*   counts   = (int*)(ws + o_cnt);
        int*   cur      = counts + n_nodes;
        int*   offs     = (int*)(ws + o_offs);
        int*   sorted   = (int*)(ws + o_sorted);
        int*   bsum     = (int*)(ws + o_bsum);
        int*   bscan    = bsum + 256;
        int*   flag     = (int*)(ws + o_flag);

        const int ch = (n_nodes + 255) / 256;          // chunk per scan block
        const int nb = (n_nodes + ch - 1) / ch;        // <= 256

        hipMemsetAsync(counts, 0, (size_t)n_nodes * sizeof(int), stream);
        hipMemsetAsync(d_out, 0, (size_t)out_size * sizeof(float), stream);
        detect_idx_kernel<<<1, 64, 0, stream>>>(eidx, flag);
        trans_kernel<<<64, 256, 0, stream>>>(Ws, Wphi, WsT, WphiT);
        hist_kernel<<<1024, 256, 0, stream>>>(eidx, flag, counts, n_edges);
        scan1_kernel<<<nb, 256, 0, stream>>>(counts, bsum, n_nodes, ch);
        scan2_kernel<<<1, 256, 0, stream>>>(bsum, bscan, offs, nb, n_nodes);
        scan3_kernel<<<nb, 256, 0, stream>>>(counts, bscan, offs, n_nodes, ch);
        hipMemcpyAsync(cur, offs, (size_t)n_nodes * sizeof(int),
                       hipMemcpyDeviceToDevice, stream);
        scatter_kernel<<<1024, 256, 0, stream>>>(eidx, flag, cur, sorted, n_edges);
        node_mlp2<<<(n_nodes + 63) / 64, 64, 0, stream>>>(node, bs, bphi, WsT, WphiT,
                                                          s_planes, plane_n, n_nodes);
        const int n_tiles = (n_edges + 63) / 64;
        accum2_kernel<<<(n_tiles + 3) / 4, 256, 0, stream>>>(
            s_planes, plane_n, eq, rbf, env, rij, eidx, flag, sorted,
            Ww, bw, ds, dv, n_edges);
    } else {
        // round-1 fallback
        float* s_ws = (float*)d_ws;
        int* idx_flag = (int*)(ws + (size_t)n_nodes * 192 * sizeof(float));
        hipMemsetAsync(d_out, 0, (size_t)out_size * sizeof(float), stream);
        detect_idx_kernel<<<1, 64, 0, stream>>>(eidx, idx_flag);
        node_mlp_kernel<<<1024, 256, 0, stream>>>(node, Ws, bs, Wphi, bphi, s_ws, n_nodes);
        edge_kernel<<<4096, 256, 0, stream>>>(s_ws, eq, rbf, env, rij, eidx, idx_flag,
                                              Ww, bw, ds, dv, n_edges);
    }
}

// Round 4
// 613.104 us; speedup vs baseline: 1.9887x; 1.2838x over previous
//
#include <hip/hip_runtime.h>

#define NRAD 20
#define MNODE 8

__device__ __forceinline__ float rdlane(float v, int l)
{
    return __uint_as_float(__builtin_amdgcn_readlane(__float_as_uint(v), l));
}

// ---------------------------------------------------------------------------
// Detect edge_index storage: int32 (flag=1) vs int64 (flag=0).
// ---------------------------------------------------------------------------
__global__ void detect_idx_kernel(const int* __restrict__ eidx, int* __restrict__ flag)
{
    int t = threadIdx.x;  // 64 threads, one wave
    unsigned long long m = __ballot(eidx[2 * t + 1] != 0);
    if (t == 0) flag[0] = (__popcll(m) > 8) ? 1 : 0;
}

// ---------------------------------------------------------------------------
// CSR build: histogram, 3-stage scan, scatter.
// ---------------------------------------------------------------------------
__global__ void hist_kernel(const int* __restrict__ eidx, const int* __restrict__ flag,
                            int* __restrict__ counts, int n_edges)
{
    int fmt32 = flag[0];
    int i0 = blockIdx.x * blockDim.x + threadIdx.x;
    int stride = gridDim.x * blockDim.x;
    if (fmt32) {
        for (int e = i0; e < n_edges; e += stride) atomicAdd(&counts[eidx[2 * e]], 1);
    } else {
        const long long* e64 = (const long long*)eidx;
        for (int e = i0; e < n_edges; e += stride) atomicAdd(&counts[(int)e64[2 * e]], 1);
    }
}

__global__ __launch_bounds__(256)
void scan1_kernel(const int* __restrict__ cnt, int* __restrict__ bsum, int n, int ch)
{
    __shared__ int red[4];
    int b = blockIdx.x, t = threadIdx.x;
    int end = min(n, (b + 1) * ch);
    int v = 0;
    for (int i = b * ch + t; i < end; i += 256) v += cnt[i];
#pragma unroll
    for (int d = 1; d < 64; d <<= 1) v += __shfl_xor(v, d, 64);
    if ((t & 63) == 0) red[t >> 6] = v;
    __syncthreads();
    if (t == 0) bsum[b] = red[0] + red[1] + red[2] + red[3];
}

__global__ __launch_bounds__(256)
void scan2_kernel(const int* __restrict__ bsum, int* __restrict__ bscan,
                  int* __restrict__ offs, int nb, int n)
{
    __shared__ int wsum[4];
    int t = threadIdx.x, lane = t & 63, w = t >> 6;
    int v = (t < nb) ? bsum[t] : 0;
    int sc = v;
#pragma unroll
    for (int d = 1; d < 64; d <<= 1) {
        int u = __shfl_up(sc, (unsigned)d, 64);
        if (lane >= d) sc += u;
    }
    if (lane == 63) wsum[w] = sc;
    __syncthreads();
    int add = 0;
    for (int j = 0; j < w; j++) add += wsum[j];
    int incl = sc + add;
    if (t < nb) bscan[t] = incl - v;
    if (t == nb - 1) offs[n] = incl;  // grand total
}

__global__ __launch_bounds__(256)
void scan3_kernel(const int* __restrict__ cnt, const int* __restrict__ bscan,
                  int* __restrict__ offs, int* __restrict__ cur, int n, int ch)
{
    __shared__ int wsum[4];
    __shared__ int btot;
    int b = blockIdx.x, t = threadIdx.x, lane = t & 63, w = t >> 6;
    int end = min(n, (b + 1) * ch);
    int carry = bscan[b];
    for (int base = b * ch; base < end; base += 256) {
        int i = base + t;
        int v = (i < end) ? cnt[i] : 0;
        int sc = v;
#pragma unroll
        for (int d = 1; d < 64; d <<= 1) {
            int u = __shfl_up(sc, (unsigned)d, 64);
            if (lane >= d) sc += u;
        }
        if (lane == 63) wsum[w] = sc;
        __syncthreads();
        int add = 0;
        for (int j = 0; j < w; j++) add += wsum[j];
        if (t == 255) btot = sc + add;
        int excl = carry + (sc + add - v);
        if (i < end) { offs[i] = excl; cur[i] = excl; }
        __syncthreads();
        carry += btot;
    }
}

__global__ void scatter_kernel(const int* __restrict__ eidx, const int* __restrict__ flag,
                               int* __restrict__ cur, int* __restrict__ sorted, int n_edges)
{
    int fmt32 = flag[0];
    int i0 = blockIdx.x * blockDim.x + threadIdx.x;
    int stride = gridDim.x * blockDim.x;
    const long long* e64 = (const long long*)eidx;
    for (int e = i0; e < n_edges; e += stride) {
        int dst = fmt32 ? eidx[2 * e] : (int)e64[2 * e];
        int pos = atomicAdd(&cur[dst], 1);
        sorted[pos] = e;
    }
}

// ---------------------------------------------------------------------------
// Node MLP v3: lane = output channel, 8 nodes per wave.
// Each LDS weight read feeds 8 nodes; x/s1 broadcast via v_readlane (VALU
// pipe, not LDS pipe). VALU floor ~384 instr/node -> ~62 us at 100% busy.
// ---------------------------------------------------------------------------
__global__ __launch_bounds__(256)
void node_mlp3(const float* __restrict__ node,
               const float* __restrict__ Ws, const float* __restrict__ bs,
               const float* __restrict__ Wphi, const float* __restrict__ bphi,
               float* __restrict__ s_planes, size_t plane_n, int n_nodes)
{
    __shared__ float WsT[64 * 64];    // [k][j] = Ws[j][k]
    __shared__ float WphiT[64 * 192]; // [k][j] = Wphi[j][k]
    const int t = threadIdx.x;
    for (int i = t; i < 64 * 64; i += 256) {
        int j = i >> 6, k = i & 63;
        WsT[k * 64 + j] = Ws[i];
    }
    for (int i = t; i < 192 * 64; i += 256) {
        int j = i >> 6, k = i & 63;
        WphiT[k * 192 + j] = Wphi[i];
    }
    __syncthreads();

    const int lane = t & 63;
    const int wave = t >> 6;
    const int gw = blockIdx.x * 4 + wave;
    const int nw = gridDim.x * 4;
    const float bsc = bs[lane];
    const float bp0 = bphi[lane], bp1 = bphi[64 + lane], bp2 = bphi[128 + lane];
    float* p0 = s_planes;
    float* p1 = s_planes + plane_n;
    float* p2 = s_planes + 2 * plane_n;

    for (int n0 = gw * MNODE; n0 < n_nodes; n0 += nw * MNODE) {
        const int cnt = min(MNODE, n_nodes - n0);
        float x[MNODE];
#pragma unroll
        for (int m = 0; m < MNODE; m++)
            x[m] = (m < cnt) ? node[(size_t)(n0 + m) * 64 + lane] : 0.f;

        float acc[MNODE];
#pragma unroll
        for (int m = 0; m < MNODE; m++) acc[m] = bsc;
#pragma unroll
        for (int k = 0; k < 64; k++) {
            float wv = WsT[k * 64 + lane];
#pragma unroll
            for (int m = 0; m < MNODE; m++) acc[m] += rdlane(x[m], k) * wv;
        }
        float s1[MNODE];
#pragma unroll
        for (int m = 0; m < MNODE; m++) {
            float a = acc[m];
            s1[m] = a / (1.f + __expf(-a));
        }
        float a0[MNODE], a1[MNODE], a2[MNODE];
#pragma unroll
        for (int m = 0; m < MNODE; m++) { a0[m] = bp0; a1[m] = bp1; a2[m] = bp2; }
#pragma unroll
        for (int k = 0; k < 64; k++) {
            float w0 = WphiT[k * 192 + lane];
            float w1 = WphiT[k * 192 + 64 + lane];
            float w2 = WphiT[k * 192 + 128 + lane];
#pragma unroll
            for (int m = 0; m < MNODE; m++) {
                float sv = rdlane(s1[m], k);
                a0[m] += sv * w0;
                a1[m] += sv * w1;
                a2[m] += sv * w2;
            }
        }
#pragma unroll
        for (int m = 0; m < MNODE; m++) {
            if (m < cnt) {
                size_t ob = (size_t)(n0 + m) * 64 + lane;
                p0[ob] = a0[m];
                p1[ob] = a1[m];
                p2[ob] = a2[m];
            }
        }
    }
}

// ---------------------------------------------------------------------------
// Tiled accumulate (unchanged from round 3 — verified, 295 us).
// ---------------------------------------------------------------------------
__global__ __launch_bounds__(256)
void accum2_kernel(const float* __restrict__ s_planes, size_t plane_n,
                   const float* __restrict__ eq, const float* __restrict__ rbf,
                   const float* __restrict__ env, const float* __restrict__ rij,
                   const int* __restrict__ eidx, const int* __restrict__ flag,
                   const int* __restrict__ sorted,
                   const float* __restrict__ Ww, const float* __restrict__ bw,
                   float* __restrict__ ds, float* __restrict__ dv,
                   int n_edges)
{
    __shared__ int    sh_dst[4 * 64];
    __shared__ int    sh_src[4 * 64];
    __shared__ float  sh_env[4 * 64];
    __shared__ float  sh_r[4 * 3 * 64];          // [w][comp][edge]
    __shared__ float4 sh_rbf[4 * 64 * 5];        // [w][edge][q]

    const int lane = threadIdx.x & 63;
    const int w = threadIdx.x >> 6;
    const int tile = blockIdx.x * 4 + w;
    const int base = tile * 64;
    const int nvalid = min(64, n_edges - base);
    const int woff = w * 64;

    // ---- Phase 1: lane = edge ----
    if (lane < nvalid) {
        int e = sorted[base + lane];
        int d_, s_;
        if (flag[0]) {
            const int2* p2 = (const int2*)eidx;
            int2 v = p2[e];
            d_ = v.x; s_ = v.y;
        } else {
            const longlong2* p2 = (const longlong2*)eidx;
            longlong2 v = p2[e];
            d_ = (int)v.x; s_ = (int)v.y;
        }
        sh_dst[woff + lane] = d_;
        sh_src[woff + lane] = s_;
        sh_env[woff + lane] = env[e];
        sh_r[w * 192 + lane]       = rij[3 * e];
        sh_r[w * 192 + 64 + lane]  = rij[3 * e + 1];
        sh_r[w * 192 + 128 + lane] = rij[3 * e + 2];
        const float4* rbf4 = (const float4*)rbf;
#pragma unroll
        for (int q = 0; q < 5; q++) sh_rbf[(woff + lane) * 5 + q] = rbf4[(size_t)e * 5 + q];
    }
    __syncthreads();

    if (nvalid <= 0) return;

    const float4* Ww4 = (const float4*)Ww;
    float4 w0q[5], w1q[5], w2q[5];
#pragma unroll
    for (int q = 0; q < 5; q++) {
        w0q[q] = Ww4[lane * 5 + q];
        w1q[q] = Ww4[(64 + lane) * 5 + q];
        w2q[q] = Ww4[(128 + lane) * 5 + q];
    }
    const float bw0 = bw[lane], bw1 = bw[64 + lane], bw2 = bw[128 + lane];

    const float* s0p = s_planes;
    const float* s1p = s_planes + plane_n;
    const float* s2p = s_planes + 2 * plane_n;

    float a0 = 0.f, a1 = 0.f, a2 = 0.f, a3 = 0.f;
    int cur = sh_dst[woff];

    // ---- Phase 2: lane = channel ----
    for (int j = 0; j < nvalid; j++) {
        int src = sh_src[woff + j];
        float ev = sh_env[woff + j];
        float r0 = sh_r[w * 192 + j];
        float r1 = sh_r[w * 192 + 64 + j];
        float r2 = sh_r[w * 192 + 128 + j];

        float w0 = bw0, w1 = bw1, w2 = bw2;
#pragma unroll
        for (int q = 0; q < 5; q++) {
            float4 rb = sh_rbf[(woff + j) * 5 + q];
            w0 += rb.x * w0q[q].x + rb.y * w0q[q].y + rb.z * w0q[q].z + rb.w * w0q[q].w;
            w1 += rb.x * w1q[q].x + rb.y * w1q[q].y + rb.z * w1q[q].z + rb.w * w1q[q].w;
            w2 += rb.x * w2q[q].x + rb.y * w2q[q].y + rb.z * w2q[q].z + rb.w * w2q[q].w;
        }
        w0 *= ev; w1 *= ev; w2 *= ev;

        size_t sb = (size_t)src * 64 + lane;
        float sw0 = s0p[sb] * w0;
        float sw1 = s1p[sb] * w1;
        float sw2 = s2p[sb] * w2;
        size_t qb = (size_t)src * 192 + lane;
        a0 += sw0;
        a1 += eq[qb] * sw1 + r0 * sw2;
        a2 += eq[qb + 64] * sw1 + r1 * sw2;
        a3 += eq[qb + 128] * sw1 + r2 * sw2;

        int nd = (j + 1 < nvalid) ? sh_dst[woff + j + 1] : -2;
        if (nd != cur) {
            unsafeAtomicAdd(&ds[(size_t)cur * 64 + lane], a0);
            size_t db = (size_t)cur * 192 + lane;
            unsafeAtomicAdd(&dv[db], a1);
            unsafeAtomicAdd(&dv[db + 64], a2);
            unsafeAtomicAdd(&dv[db + 128], a3);
            a0 = a1 = a2 = a3 = 0.f;
            cur = nd;
        }
    }
}

// ===========================================================================
// Fallback path (round-1, proven): row-major s + atomic scatter.
// ===========================================================================
__global__ __launch_bounds__(256, 2)
void node_mlp_kernel(const float* __restrict__ node,
                     const float* __restrict__ Ws,
                     const float* __restrict__ bs,
                     const float* __restrict__ Wphi,
                     const float* __restrict__ bphi,
                     float* __restrict__ s_out,
                     int n_nodes)
{
    __shared__ float WsT[64 * 65];
    __shared__ float WphiT[64 * 193];
    const int t = threadIdx.x;
    for (int i = t; i < 64 * 64; i += 256) {
        int c = i >> 6, k = i & 63;
        WsT[k * 65 + c] = Ws[i];
    }
    for (int i = t; i < 192 * 64; i += 256) {
        int j = i >> 6, k = i & 63;
        WphiT[k * 193 + j] = Wphi[i];
    }
    __syncthreads();

    const int lane = t & 63;
    const int wave = t >> 6;
    const int nwaves = (gridDim.x * blockDim.x) >> 6;
    const float bsc = bs[lane];
    const float bp0 = bphi[lane], bp1 = bphi[64 + lane], bp2 = bphi[128 + lane];

    for (int n = blockIdx.x * 4 + wave; n < n_nodes; n += nwaves) {
        float x = node[(size_t)n * 64 + lane];
        float acc = bsc;
#pragma unroll
        for (int k = 0; k < 64; k++) acc += __shfl(x, k) * WsT[k * 65 + lane];
        float s1 = acc / (1.0f + __expf(-acc));
        float a0 = bp0, a1 = bp1, a2 = bp2;
#pragma unroll
        for (int k = 0; k < 64; k++) {
            float sk = __shfl(s1, k);
            a0 += sk * WphiT[k * 193 + lane];
            a1 += sk * WphiT[k * 193 + 64 + lane];
            a2 += sk * WphiT[k * 193 + 128 + lane];
        }
        size_t ob = (size_t)n * 192;
        s_out[ob + lane] = a0;
        s_out[ob + 64 + lane] = a1;
        s_out[ob + 128 + lane] = a2;
    }
}

__global__ __launch_bounds__(256)
void edge_kernel(const float* __restrict__ s,
                 const float* __restrict__ eq,
                 const float* __restrict__ rbf,
                 const float* __restrict__ env,
                 const float* __restrict__ rij,
                 const int* __restrict__ eidx,
                 const int* __restrict__ idx_flag,
                 const float* __restrict__ Ww,
                 const float* __restrict__ bw,
                 float* __restrict__ ds,
                 float* __restrict__ dv,
                 int n_edges)
{
    const int lane = threadIdx.x & 63;
    const int wglob = (blockIdx.x * blockDim.x + threadIdx.x) >> 6;
    const int nw = (gridDim.x * blockDim.x) >> 6;

    float ww0[NRAD], ww1[NRAD], ww2[NRAD];
#pragma unroll
    for (int k = 0; k < NRAD; k++) {
        ww0[k] = Ww[lane * NRAD + k];
        ww1[k] = Ww[(64 + lane) * NRAD + k];
        ww2[k] = Ww[(128 + lane) * NRAD + k];
    }
    const float bw0 = bw[lane], bw1 = bw[64 + lane], bw2 = bw[128 + lane];
    const int fmt32 = idx_flag[0];

    for (int e = wglob; e < n_edges; e += nw) {
        int dst, src;
        if (fmt32) {
            dst = eidx[2 * e];
            src = eidx[2 * e + 1];
        } else {
            const long long* e64 = (const long long*)eidx;
            dst = (int)e64[2 * e];
            src = (int)e64[2 * e + 1];
        }
        float ev = env[e];
        float r0 = rij[3 * e], r1 = rij[3 * e + 1], r2 = rij[3 * e + 2];
        float rb[NRAD];
#pragma unroll
        for (int k = 0; k < NRAD; k++) rb[k] = rbf[(size_t)e * NRAD + k];
        float w0 = bw0, w1 = bw1, w2 = bw2;
#pragma unroll
        for (int k = 0; k < NRAD; k++) {
            w0 += rb[k] * ww0[k];
            w1 += rb[k] * ww1[k];
            w2 += rb[k] * ww2[k];
        }
        w0 *= ev; w1 *= ev; w2 *= ev;

        size_t sb = (size_t)src * 192;
        float sw0 = s[sb + lane] * w0;
        float sw1 = s[sb + 64 + lane] * w1;
        float sw2 = s[sb + 128 + lane] * w2;
        float v0 = eq[sb + lane];
        float v1 = eq[sb + 64 + lane];
        float v2 = eq[sb + 128 + lane];

        unsafeAtomicAdd(&ds[(size_t)dst * 64 + lane], sw0);
        size_t db = (size_t)dst * 192;
        unsafeAtomicAdd(&dv[db + lane],       v0 * sw1 + r0 * sw2);
        unsafeAtomicAdd(&dv[db + 64 + lane],  v1 * sw1 + r1 * sw2);
        unsafeAtomicAdd(&dv[db + 128 + lane], v2 * sw1 + r2 * sw2);
    }
}

extern "C" void kernel_launch(void* const* d_in, const int* in_sizes, int n_in,
                              void* d_out, int out_size, void* d_ws, size_t ws_size,
                              hipStream_t stream)
{
    const float* node = (const float*)d_in[0];
    const float* eq   = (const float*)d_in[1];
    const float* rbf  = (const float*)d_in[2];
    const float* env  = (const float*)d_in[3];
    const float* rij  = (const float*)d_in[4];
    const int*   eidx = (const int*)d_in[5];
    const float* Ws   = (const float*)d_in[6];
    const float* bs   = (const float*)d_in[7];
    const float* Wphi = (const float*)d_in[8];
    const float* bphi = (const float*)d_in[9];
    const float* Ww   = (const float*)d_in[10];
    const float* bw   = (const float*)d_in[11];

    const int n_nodes = in_sizes[0] / 64;
    const int n_edges = in_sizes[3];

    float* out = (float*)d_out;
    float* ds = out;
    float* dv = out + (size_t)n_nodes * 64;

    // ws layout (256B aligned slots)
    size_t off = 0;
    auto alloc = [&](size_t bytes) { size_t o = off; off = (off + bytes + 255) & ~(size_t)255; return o; };
    const size_t plane_n = (size_t)n_nodes * 64;
    size_t o_planes = alloc(3 * plane_n * sizeof(float));
    size_t o_cnt    = alloc(2 * (size_t)n_nodes * sizeof(int));   // counts + cur
    size_t o_offs   = alloc(((size_t)n_nodes + 1) * sizeof(int));
    size_t o_sorted = alloc((size_t)n_edges * sizeof(int));
    size_t o_bsum   = alloc(512 * sizeof(int));                   // bsum + bscan
    size_t o_flag   = alloc(16);
    size_t needed = off;

    char* ws = (char*)d_ws;

    if (ws_size >= needed) {
        float* s_planes = (float*)(ws + o_planes);
        int*   counts   = (int*)(ws + o_cnt);
        int*   cur      = counts + n_nodes;
        int*   offs     = (int*)(ws + o_offs);
        int*   sorted   = (int*)(ws + o_sorted);
        int*   bsum     = (int*)(ws + o_bsum);
        int*   bscan    = bsum + 256;
        int*   flag     = (int*)(ws + o_flag);

        const int ch = (n_nodes + 255) / 256;          // chunk per scan block
        const int nb = (n_nodes + ch - 1) / ch;        // <= 256

        hipMemsetAsync(counts, 0, (size_t)n_nodes * sizeof(int), stream);
        hipMemsetAsync(d_out, 0, (size_t)out_size * sizeof(float), stream);
        detect_idx_kernel<<<1, 64, 0, stream>>>(eidx, flag);
        hist_kernel<<<1024, 256, 0, stream>>>(eidx, flag, counts, n_edges);
        scan1_kernel<<<nb, 256, 0, stream>>>(counts, bsum, n_nodes, ch);
        scan2_kernel<<<1, 256, 0, stream>>>(bsum, bscan, offs, nb, n_nodes);
        scan3_kernel<<<nb, 256, 0, stream>>>(counts, bscan, offs, cur, n_nodes, ch);
        scatter_kernel<<<1024, 256, 0, stream>>>(eidx, flag, cur, sorted, n_edges);
        node_mlp3<<<512, 256, 0, stream>>>(node, Ws, bs, Wphi, bphi,
                                           s_planes, plane_n, n_nodes);
        const int n_tiles = (n_edges + 63) / 64;
        accum2_kernel<<<(n_tiles + 3) / 4, 256, 0, stream>>>(
            s_planes, plane_n, eq, rbf, env, rij, eidx, flag, sorted,
            Ww, bw, ds, dv, n_edges);
    } else {
        // round-1 fallback
        float* s_ws = (float*)d_ws;
        int* idx_flag = (int*)(ws + (size_t)n_nodes * 192 * sizeof(float));
        hipMemsetAsync(d_out, 0, (size_t)out_size * sizeof(float), stream);
        detect_idx_kernel<<<1, 64, 0, stream>>>(eidx, idx_flag);
        node_mlp_kernel<<<1024, 256, 0, stream>>>(node, Ws, bs, Wphi, bphi, s_ws, n_nodes);
        edge_kernel<<<4096, 256, 0, stream>>>(s_ws, eq, rbf, env, rij, eidx, idx_flag,
                                              Ww, bw, ds, dv, n_edges);
    }
}

// Round 5
// 598.158 us; speedup vs baseline: 2.0384x; 1.0250x over previous
//
#include <hip/hip_runtime.h>

#define NRAD 20
#define MNODE 8

typedef unsigned short ushort_t;
typedef unsigned int uint_t;

__device__ __forceinline__ float rdlane(float v, int l)
{
    return __uint_as_float(__builtin_amdgcn_readlane(__float_as_uint(v), l));
}

__device__ __forceinline__ ushort_t f2bf(float f)
{
    uint_t u = __float_as_uint(f);
    u += 0x7fff + ((u >> 16) & 1);   // round-to-nearest-even
    return (ushort_t)(u >> 16);
}

__device__ __forceinline__ uint_t pack2bf(float a, float b)
{
    return (uint_t)f2bf(a) | ((uint_t)f2bf(b) << 16);
}

__device__ __forceinline__ float bflo(uint_t w) { return __uint_as_float(w << 16); }
__device__ __forceinline__ float bfhi(uint_t w) { return __uint_as_float(w & 0xffff0000u); }
__device__ __forceinline__ float bf2f(ushort_t h) { return __uint_as_float(((uint_t)h) << 16); }

// ---------------------------------------------------------------------------
// Detect edge_index storage: int32 (flag=1) vs int64 (flag=0).
// ---------------------------------------------------------------------------
__global__ void detect_idx_kernel(const int* __restrict__ eidx, int* __restrict__ flag)
{
    int t = threadIdx.x;  // 64 threads, one wave
    unsigned long long m = __ballot(eidx[2 * t + 1] != 0);
    if (t == 0) flag[0] = (__popcll(m) > 8) ? 1 : 0;
}

// ---------------------------------------------------------------------------
// CSR build: histogram, 3-stage scan -> cur, then record-building scatter.
// ---------------------------------------------------------------------------
__global__ void hist_kernel(const int* __restrict__ eidx, const int* __restrict__ flag,
                            int* __restrict__ counts, int n_edges)
{
    int fmt32 = flag[0];
    int i0 = blockIdx.x * blockDim.x + threadIdx.x;
    int stride = gridDim.x * blockDim.x;
    if (fmt32) {
        for (int e = i0; e < n_edges; e += stride) atomicAdd(&counts[eidx[2 * e]], 1);
    } else {
        const long long* e64 = (const long long*)eidx;
        for (int e = i0; e < n_edges; e += stride) atomicAdd(&counts[(int)e64[2 * e]], 1);
    }
}

__global__ __launch_bounds__(256)
void scan1_kernel(const int* __restrict__ cnt, int* __restrict__ bsum, int n, int ch)
{
    __shared__ int red[4];
    int b = blockIdx.x, t = threadIdx.x;
    int end = min(n, (b + 1) * ch);
    int v = 0;
    for (int i = b * ch + t; i < end; i += 256) v += cnt[i];
#pragma unroll
    for (int d = 1; d < 64; d <<= 1) v += __shfl_xor(v, d, 64);
    if ((t & 63) == 0) red[t >> 6] = v;
    __syncthreads();
    if (t == 0) bsum[b] = red[0] + red[1] + red[2] + red[3];
}

__global__ __launch_bounds__(256)
void scan2_kernel(const int* __restrict__ bsum, int* __restrict__ bscan, int nb)
{
    __shared__ int wsum[4];
    int t = threadIdx.x, lane = t & 63, w = t >> 6;
    int v = (t < nb) ? bsum[t] : 0;
    int sc = v;
#pragma unroll
    for (int d = 1; d < 64; d <<= 1) {
        int u = __shfl_up(sc, (unsigned)d, 64);
        if (lane >= d) sc += u;
    }
    if (lane == 63) wsum[w] = sc;
    __syncthreads();
    int add = 0;
    for (int j = 0; j < w; j++) add += wsum[j];
    if (t < nb) bscan[t] = (sc + add) - v;
}

__global__ __launch_bounds__(256)
void scan3_kernel(const int* __restrict__ cnt, const int* __restrict__ bscan,
                  int* __restrict__ cur, int n, int ch)
{
    __shared__ int wsum[4];
    __shared__ int btot;
    int b = blockIdx.x, t = threadIdx.x, lane = t & 63, w = t >> 6;
    int end = min(n, (b + 1) * ch);
    int carry = bscan[b];
    for (int base = b * ch; base < end; base += 256) {
        int i = base + t;
        int v = (i < end) ? cnt[i] : 0;
        int sc = v;
#pragma unroll
        for (int d = 1; d < 64; d <<= 1) {
            int u = __shfl_up(sc, (unsigned)d, 64);
            if (lane >= d) sc += u;
        }
        if (lane == 63) wsum[w] = sc;
        __syncthreads();
        int add = 0;
        for (int j = 0; j < w; j++) add += wsum[j];
        if (t == 255) btot = sc + add;
        int excl = carry + (sc + add - v);
        if (i < end) cur[i] = excl;
        __syncthreads();
        carry += btot;
    }
}

// T1: build 64-byte sorted edge records. Reads streams coalesced (original
// edge order); one random 64 B write per edge.
// rec layout (4x uint4): {src,dst,env,r0} {r1,r2,w0,w1} {w2..w5} {w6..w9},
// wi = packed bf16 pair of rbf[2i],rbf[2i+1].
__global__ void scatter_rec_kernel(const int* __restrict__ eidx, const int* __restrict__ flag,
                                   int* __restrict__ cur,
                                   const float* __restrict__ env, const float* __restrict__ rij,
                                   const float* __restrict__ rbf,
                                   uint4* __restrict__ rec, int n_edges)
{
    int fmt32 = flag[0];
    int i0 = blockIdx.x * blockDim.x + threadIdx.x;
    int stride = gridDim.x * blockDim.x;
    const long long* e64 = (const long long*)eidx;
    const float4* rbf4 = (const float4*)rbf;
    for (int e = i0; e < n_edges; e += stride) {
        int dst, src;
        if (fmt32) { dst = eidx[2 * e]; src = eidx[2 * e + 1]; }
        else       { dst = (int)e64[2 * e]; src = (int)e64[2 * e + 1]; }
        int pos = atomicAdd(&cur[dst], 1);
        float ev = env[e];
        float r0 = rij[3 * e], r1 = rij[3 * e + 1], r2 = rij[3 * e + 2];
        float4 b0 = rbf4[(size_t)e * 5 + 0];
        float4 b1 = rbf4[(size_t)e * 5 + 1];
        float4 b2 = rbf4[(size_t)e * 5 + 2];
        float4 b3 = rbf4[(size_t)e * 5 + 3];
        float4 b4 = rbf4[(size_t)e * 5 + 4];
        uint4 qa, qb, qc, qd;
        qa.x = (uint_t)src; qa.y = (uint_t)dst;
        qa.z = __float_as_uint(ev); qa.w = __float_as_uint(r0);
        qb.x = __float_as_uint(r1); qb.y = __float_as_uint(r2);
        qb.z = pack2bf(b0.x, b0.y); qb.w = pack2bf(b0.z, b0.w);
        qc.x = pack2bf(b1.x, b1.y); qc.y = pack2bf(b1.z, b1.w);
        qc.z = pack2bf(b2.x, b2.y); qc.w = pack2bf(b2.z, b2.w);
        qd.x = pack2bf(b3.x, b3.y); qd.y = pack2bf(b3.z, b3.w);
        qd.z = pack2bf(b4.x, b4.y); qd.w = pack2bf(b4.z, b4.w);
        size_t rp = (size_t)pos * 4;
        rec[rp] = qa; rec[rp + 1] = qb; rec[rp + 2] = qc; rec[rp + 3] = qd;
    }
}

// T2: plain index scatter (fallback when rec doesn't fit ws).
__global__ void scatter_kernel(const int* __restrict__ eidx, const int* __restrict__ flag,
                               int* __restrict__ cur, int* __restrict__ sorted, int n_edges)
{
    int fmt32 = flag[0];
    int i0 = blockIdx.x * blockDim.x + threadIdx.x;
    int stride = gridDim.x * blockDim.x;
    const long long* e64 = (const long long*)eidx;
    for (int e = i0; e < n_edges; e += stride) {
        int dst = fmt32 ? eidx[2 * e] : (int)e64[2 * e];
        int pos = atomicAdd(&cur[dst], 1);
        sorted[pos] = e;
    }
}

// ---------------------------------------------------------------------------
// eq (n,3,64) f32 -> 3 planar bf16 arrays [n][64].
// ---------------------------------------------------------------------------
__global__ void eq_cast_kernel(const float* __restrict__ eq,
                               ushort_t* __restrict__ p0, ushort_t* __restrict__ p1,
                               ushort_t* __restrict__ p2, int n_nodes)
{
    int i0 = blockIdx.x * blockDim.x + threadIdx.x;
    int stride = gridDim.x * blockDim.x;
    int total = n_nodes * 192;
    for (int i = i0; i < total; i += stride) {
        int n = i / 192;
        int r = i - n * 192;
        int c = r >> 6, ch = r & 63;
        ushort_t v = f2bf(eq[i]);
        ushort_t* p = (c == 0) ? p0 : (c == 1) ? p1 : p2;
        p[(size_t)n * 64 + ch] = v;
    }
}

// ---------------------------------------------------------------------------
// Node MLP v3 (round-4 verified structure), bf16 planar output.
// ---------------------------------------------------------------------------
__global__ __launch_bounds__(256)
void node_mlp3b(const float* __restrict__ node,
                const float* __restrict__ Ws, const float* __restrict__ bs,
                const float* __restrict__ Wphi, const float* __restrict__ bphi,
                ushort_t* __restrict__ p0, ushort_t* __restrict__ p1,
                ushort_t* __restrict__ p2, int n_nodes)
{
    __shared__ float WsT[64 * 64];    // [k][j] = Ws[j][k]
    __shared__ float WphiT[64 * 192]; // [k][j] = Wphi[j][k]
    const int t = threadIdx.x;
    for (int i = t; i < 64 * 64; i += 256) {
        int j = i >> 6, k = i & 63;
        WsT[k * 64 + j] = Ws[i];
    }
    for (int i = t; i < 192 * 64; i += 256) {
        int j = i >> 6, k = i & 63;
        WphiT[k * 192 + j] = Wphi[i];
    }
    __syncthreads();

    const int lane = t & 63;
    const int wave = t >> 6;
    const int gw = blockIdx.x * 4 + wave;
    const int nw = gridDim.x * 4;
    const float bsc = bs[lane];
    const float bp0 = bphi[lane], bp1 = bphi[64 + lane], bp2 = bphi[128 + lane];

    for (int n0 = gw * MNODE; n0 < n_nodes; n0 += nw * MNODE) {
        const int cnt = min(MNODE, n_nodes - n0);
        float x[MNODE];
#pragma unroll
        for (int m = 0; m < MNODE; m++)
            x[m] = (m < cnt) ? node[(size_t)(n0 + m) * 64 + lane] : 0.f;

        float acc[MNODE];
#pragma unroll
        for (int m = 0; m < MNODE; m++) acc[m] = bsc;
#pragma unroll
        for (int k = 0; k < 64; k++) {
            float wv = WsT[k * 64 + lane];
#pragma unroll
            for (int m = 0; m < MNODE; m++) acc[m] += rdlane(x[m], k) * wv;
        }
        float s1[MNODE];
#pragma unroll
        for (int m = 0; m < MNODE; m++) {
            float a = acc[m];
            s1[m] = a / (1.f + __expf(-a));
        }
        float a0[MNODE], a1[MNODE], a2[MNODE];
#pragma unroll
        for (int m = 0; m < MNODE; m++) { a0[m] = bp0; a1[m] = bp1; a2[m] = bp2; }
#pragma unroll
        for (int k = 0; k < 64; k++) {
            float w0 = WphiT[k * 192 + lane];
            float w1 = WphiT[k * 192 + 64 + lane];
            float w2 = WphiT[k * 192 + 128 + lane];
#pragma unroll
            for (int m = 0; m < MNODE; m++) {
                float sv = rdlane(s1[m], k);
                a0[m] += sv * w0;
                a1[m] += sv * w1;
                a2[m] += sv * w2;
            }
        }
#pragma unroll
        for (int m = 0; m < MNODE; m++) {
            if (m < cnt) {
                size_t ob = (size_t)(n0 + m) * 64 + lane;
                p0[ob] = f2bf(a0[m]);
                p1[ob] = f2bf(a1[m]);
                p2[ob] = f2bf(a2[m]);
            }
        }
    }
}

// ---------------------------------------------------------------------------
// Tiled accumulate v3: bf16 gathers; metadata from 64B records (USE_REC) or
// from sorted-index random reads (T2 fallback).
// ---------------------------------------------------------------------------
template <bool USE_REC>
__global__ __launch_bounds__(256)
void accum3_kernel(const ushort_t* __restrict__ s0p, const ushort_t* __restrict__ s1p,
                   const ushort_t* __restrict__ s2p,
                   const ushort_t* __restrict__ q0p, const ushort_t* __restrict__ q1p,
                   const ushort_t* __restrict__ q2p,
                   const uint4* __restrict__ rec,
                   const float* __restrict__ rbf, const float* __restrict__ env,
                   const float* __restrict__ rij, const int* __restrict__ eidx,
                   const int* __restrict__ flag, const int* __restrict__ sorted,
                   const float* __restrict__ Ww, const float* __restrict__ bw,
                   float* __restrict__ ds, float* __restrict__ dv, int n_edges)
{
    __shared__ int    sh_dst[4 * 64];
    __shared__ int    sh_src[4 * 64];
    __shared__ float  sh_env[4 * 64];
    __shared__ float  sh_r[4 * 3 * 64];          // [w][comp][edge]
    __shared__ float4 sh_rbf[4 * 64 * 5];        // [w][edge][q]

    const int lane = threadIdx.x & 63;
    const int w = threadIdx.x >> 6;
    const int tile = blockIdx.x * 4 + w;
    const int base = tile * 64;
    const int nvalid = min(64, n_edges - base);
    const int woff = w * 64;

    // ---- Phase 1: lane = edge ----
    if (lane < nvalid) {
        if (USE_REC) {
            size_t rp = (size_t)(base + lane) * 4;
            uint4 qa = rec[rp], qb = rec[rp + 1], qc = rec[rp + 2], qd = rec[rp + 3];
            sh_src[woff + lane] = (int)qa.x;
            sh_dst[woff + lane] = (int)qa.y;
            sh_env[woff + lane] = __uint_as_float(qa.z);
            sh_r[w * 192 + lane]       = __uint_as_float(qa.w);
            sh_r[w * 192 + 64 + lane]  = __uint_as_float(qb.x);
            sh_r[w * 192 + 128 + lane] = __uint_as_float(qb.y);
            float4* dstq = &sh_rbf[(woff + lane) * 5];
            dstq[0] = make_float4(bflo(qb.z), bfhi(qb.z), bflo(qb.w), bfhi(qb.w));
            dstq[1] = make_float4(bflo(qc.x), bfhi(qc.x), bflo(qc.y), bfhi(qc.y));
            dstq[2] = make_float4(bflo(qc.z), bfhi(qc.z), bflo(qc.w), bfhi(qc.w));
            dstq[3] = make_float4(bflo(qd.x), bfhi(qd.x), bflo(qd.y), bfhi(qd.y));
            dstq[4] = make_float4(bflo(qd.z), bfhi(qd.z), bflo(qd.w), bfhi(qd.w));
        } else {
            int e = sorted[base + lane];
            int d_, s_;
            if (flag[0]) {
                const int2* p2 = (const int2*)eidx;
                int2 v = p2[e];
                d_ = v.x; s_ = v.y;
            } else {
                const longlong2* p2 = (const longlong2*)eidx;
                longlong2 v = p2[e];
                d_ = (int)v.x; s_ = (int)v.y;
            }
            sh_dst[woff + lane] = d_;
            sh_src[woff + lane] = s_;
            sh_env[woff + lane] = env[e];
            sh_r[w * 192 + lane]       = rij[3 * e];
            sh_r[w * 192 + 64 + lane]  = rij[3 * e + 1];
            sh_r[w * 192 + 128 + lane] = rij[3 * e + 2];
            const float4* rbf4 = (const float4*)rbf;
#pragma unroll
            for (int q = 0; q < 5; q++) sh_rbf[(woff + lane) * 5 + q] = rbf4[(size_t)e * 5 + q];
        }
    }
    __syncthreads();

    if (nvalid <= 0) return;

    const float4* Ww4 = (const float4*)Ww;
    float4 w0q[5], w1q[5], w2q[5];
#pragma unroll
    for (int q = 0; q < 5; q++) {
        w0q[q] = Ww4[lane * 5 + q];
        w1q[q] = Ww4[(64 + lane) * 5 + q];
        w2q[q] = Ww4[(128 + lane) * 5 + q];
    }
    const float bw0 = bw[lane], bw1 = bw[64 + lane], bw2 = bw[128 + lane];

    float a0 = 0.f, a1 = 0.f, a2 = 0.f, a3 = 0.f;
    int cur = sh_dst[woff];

    // ---- Phase 2: lane = channel ----
    for (int j = 0; j < nvalid; j++) {
        int src = sh_src[woff + j];
        float ev = sh_env[woff + j];
        float r0 = sh_r[w * 192 + j];
        float r1 = sh_r[w * 192 + 64 + j];
        float r2 = sh_r[w * 192 + 128 + j];

        size_t sb = (size_t)src * 64 + lane;
        float sv0 = bf2f(s0p[sb]);
        float sv1 = bf2f(s1p[sb]);
        float sv2 = bf2f(s2p[sb]);
        float v0 = bf2f(q0p[sb]);
        float v1 = bf2f(q1p[sb]);
        float v2 = bf2f(q2p[sb]);

        float w0 = bw0, w1 = bw1, w2 = bw2;
#pragma unroll
        for (int q = 0; q < 5; q++) {
            float4 rb = sh_rbf[(woff + j) * 5 + q];
            w0 += rb.x * w0q[q].x + rb.y * w0q[q].y + rb.z * w0q[q].z + rb.w * w0q[q].w;
            w1 += rb.x * w1q[q].x + rb.y * w1q[q].y + rb.z * w1q[q].z + rb.w * w1q[q].w;
            w2 += rb.x * w2q[q].x + rb.y * w2q[q].y + rb.z * w2q[q].z + rb.w * w2q[q].w;
        }
        w0 *= ev; w1 *= ev; w2 *= ev;

        float sw1 = sv1 * w1;
        float sw2 = sv2 * w2;
        a0 += sv0 * w0;
        a1 += v0 * sw1 + r0 * sw2;
        a2 += v1 * sw1 + r1 * sw2;
        a3 += v2 * sw1 + r2 * sw2;

        int nd = (j + 1 < nvalid) ? sh_dst[woff + j + 1] : -2;
        if (nd != cur) {
            unsafeAtomicAdd(&ds[(size_t)cur * 64 + lane], a0);
            size_t db = (size_t)cur * 192 + lane;
            unsafeAtomicAdd(&dv[db], a1);
            unsafeAtomicAdd(&dv[db + 64], a2);
            unsafeAtomicAdd(&dv[db + 128], a3);
            a0 = a1 = a2 = a3 = 0.f;
            cur = nd;
        }
    }
}

// ===========================================================================
// T3 fallback (round-1, proven): row-major f32 s + atomic scatter.
// ===========================================================================
__global__ __launch_bounds__(256, 2)
void node_mlp_kernel(const float* __restrict__ node,
                     const float* __restrict__ Ws,
                     const float* __restrict__ bs,
                     const float* __restrict__ Wphi,
                     const float* __restrict__ bphi,
                     float* __restrict__ s_out,
                     int n_nodes)
{
    __shared__ float WsT[64 * 65];
    __shared__ float WphiT[64 * 193];
    const int t = threadIdx.x;
    for (int i = t; i < 64 * 64; i += 256) {
        int c = i >> 6, k = i & 63;
        WsT[k * 65 + c] = Ws[i];
    }
    for (int i = t; i < 192 * 64; i += 256) {
        int j = i >> 6, k = i & 63;
        WphiT[k * 193 + j] = Wphi[i];
    }
    __syncthreads();

    const int lane = t & 63;
    const int wave = t >> 6;
    const int nwaves = (gridDim.x * blockDim.x) >> 6;
    const float bsc = bs[lane];
    const float bp0 = bphi[lane], bp1 = bphi[64 + lane], bp2 = bphi[128 + lane];

    for (int n = blockIdx.x * 4 + wave; n < n_nodes; n += nwaves) {
        float x = node[(size_t)n * 64 + lane];
        float acc = bsc;
#pragma unroll
        for (int k = 0; k < 64; k++) acc += __shfl(x, k) * WsT[k * 65 + lane];
        float s1 = acc / (1.0f + __expf(-acc));
        float a0 = bp0, a1 = bp1, a2 = bp2;
#pragma unroll
        for (int k = 0; k < 64; k++) {
            float sk = __shfl(s1, k);
            a0 += sk * WphiT[k * 193 + lane];
            a1 += sk * WphiT[k * 193 + 64 + lane];
            a2 += sk * WphiT[k * 193 + 128 + lane];
        }
        size_t ob = (size_t)n * 192;
        s_out[ob + lane] = a0;
        s_out[ob + 64 + lane] = a1;
        s_out[ob + 128 + lane] = a2;
    }
}

__global__ __launch_bounds__(256)
void edge_kernel(const float* __restrict__ s,
                 const float* __restrict__ eq,
                 const float* __restrict__ rbf,
                 const float* __restrict__ env,
                 const float* __restrict__ rij,
                 const int* __restrict__ eidx,
                 const int* __restrict__ idx_flag,
                 const float* __restrict__ Ww,
                 const float* __restrict__ bw,
                 float* __restrict__ ds,
                 float* __restrict__ dv,
                 int n_edges)
{
    const int lane = threadIdx.x & 63;
    const int wglob = (blockIdx.x * blockDim.x + threadIdx.x) >> 6;
    const int nw = (gridDim.x * blockDim.x) >> 6;

    float ww0[NRAD], ww1[NRAD], ww2[NRAD];
#pragma unroll
    for (int k = 0; k < NRAD; k++) {
        ww0[k] = Ww[lane * NRAD + k];
        ww1[k] = Ww[(64 + lane) * NRAD + k];
        ww2[k] = Ww[(128 + lane) * NRAD + k];
    }
    const float bw0 = bw[lane], bw1 = bw[64 + lane], bw2 = bw[128 + lane];
    const int fmt32 = idx_flag[0];

    for (int e = wglob; e < n_edges; e += nw) {
        int dst, src;
        if (fmt32) {
            dst = eidx[2 * e];
            src = eidx[2 * e + 1];
        } else {
            const long long* e64 = (const long long*)eidx;
            dst = (int)e64[2 * e];
            src = (int)e64[2 * e + 1];
        }
        float ev = env[e];
        float r0 = rij[3 * e], r1 = rij[3 * e + 1], r2 = rij[3 * e + 2];
        float rb[NRAD];
#pragma unroll
        for (int k = 0; k < NRAD; k++) rb[k] = rbf[(size_t)e * NRAD + k];
        float w0 = bw0, w1 = bw1, w2 = bw2;
#pragma unroll
        for (int k = 0; k < NRAD; k++) {
            w0 += rb[k] * ww0[k];
            w1 += rb[k] * ww1[k];
            w2 += rb[k] * ww2[k];
        }
        w0 *= ev; w1 *= ev; w2 *= ev;

        size_t sb = (size_t)src * 192;
        float sw0 = s[sb + lane] * w0;
        float sw1 = s[sb + 64 + lane] * w1;
        float sw2 = s[sb + 128 + lane] * w2;
        float v0 = eq[sb + lane];
        float v1 = eq[sb + 64 + lane];
        float v2 = eq[sb + 128 + lane];

        unsafeAtomicAdd(&ds[(size_t)dst * 64 + lane], sw0);
        size_t db = (size_t)dst * 192;
        unsafeAtomicAdd(&dv[db + lane],       v0 * sw1 + r0 * sw2);
        unsafeAtomicAdd(&dv[db + 64 + lane],  v1 * sw1 + r1 * sw2);
        unsafeAtomicAdd(&dv[db + 128 + lane], v2 * sw1 + r2 * sw2);
    }
}

extern "C" void kernel_launch(void* const* d_in, const int* in_sizes, int n_in,
                              void* d_out, int out_size, void* d_ws, size_t ws_size,
                              hipStream_t stream)
{
    const float* node = (const float*)d_in[0];
    const float* eq   = (const float*)d_in[1];
    const float* rbf  = (const float*)d_in[2];
    const float* env  = (const float*)d_in[3];
    const float* rij  = (const float*)d_in[4];
    const int*   eidx = (const int*)d_in[5];
    const float* Ws   = (const float*)d_in[6];
    const float* bs   = (const float*)d_in[7];
    const float* Wphi = (const float*)d_in[8];
    const float* bphi = (const float*)d_in[9];
    const float* Ww   = (const float*)d_in[10];
    const float* bw   = (const float*)d_in[11];

    const int n_nodes = in_sizes[0] / 64;
    const int n_edges = in_sizes[3];

    float* out = (float*)d_out;
    float* ds = out;
    float* dv = out + (size_t)n_nodes * 64;
    char* ws = (char*)d_ws;

    const size_t plane_n = (size_t)n_nodes * 64;
    const int ch = (n_nodes + 255) / 256;
    const int nb = (n_nodes + ch - 1) / ch;

    // ---- Tier-1 layout: bf16 planes + 64B records ----
    {
        size_t off = 0;
        auto alloc = [&](size_t bytes) { size_t o = off; off = (off + bytes + 255) & ~(size_t)255; return o; };
        size_t o_sp   = alloc(3 * plane_n * sizeof(ushort_t));
        size_t o_qp   = alloc(3 * plane_n * sizeof(ushort_t));
        size_t o_cnt  = alloc(2 * (size_t)n_nodes * sizeof(int));    // counts + cur
        size_t o_rec  = alloc((size_t)n_edges * 64);
        size_t o_bsum = alloc(512 * sizeof(int));
        size_t o_flag = alloc(16);
        if (ws_size >= off) {
            ushort_t* sp = (ushort_t*)(ws + o_sp);
            ushort_t* qp = (ushort_t*)(ws + o_qp);
            int* counts = (int*)(ws + o_cnt);
            int* cur = counts + n_nodes;
            uint4* rec = (uint4*)(ws + o_rec);
            int* bsum = (int*)(ws + o_bsum);
            int* bscan = bsum + 256;
            int* flag = (int*)(ws + o_flag);

            hipMemsetAsync(counts, 0, (size_t)n_nodes * sizeof(int), stream);
            hipMemsetAsync(d_out, 0, (size_t)out_size * sizeof(float), stream);
            detect_idx_kernel<<<1, 64, 0, stream>>>(eidx, flag);
            hist_kernel<<<1024, 256, 0, stream>>>(eidx, flag, counts, n_edges);
            scan1_kernel<<<nb, 256, 0, stream>>>(counts, bsum, n_nodes, ch);
            scan2_kernel<<<1, 256, 0, stream>>>(bsum, bscan, nb);
            scan3_kernel<<<nb, 256, 0, stream>>>(counts, bscan, cur, n_nodes, ch);
            scatter_rec_kernel<<<1024, 256, 0, stream>>>(eidx, flag, cur, env, rij, rbf,
                                                         rec, n_edges);
            eq_cast_kernel<<<1024, 256, 0, stream>>>(eq, qp, qp + plane_n, qp + 2 * plane_n,
                                                     n_nodes);
            node_mlp3b<<<512, 256, 0, stream>>>(node, Ws, bs, Wphi, bphi,
                                                sp, sp + plane_n, sp + 2 * plane_n, n_nodes);
            const int n_tiles = (n_edges + 63) / 64;
            accum3_kernel<true><<<(n_tiles + 3) / 4, 256, 0, stream>>>(
                sp, sp + plane_n, sp + 2 * plane_n,
                qp, qp + plane_n, qp + 2 * plane_n,
                rec, rbf, env, rij, eidx, flag, (const int*)nullptr,
                Ww, bw, ds, dv, n_edges);
            return;
        }
    }

    // ---- Tier-2 layout: bf16 planes + sorted index (no records) ----
    {
        size_t off = 0;
        auto alloc = [&](size_t bytes) { size_t o = off; off = (off + bytes + 255) & ~(size_t)255; return o; };
        size_t o_sp   = alloc(3 * plane_n * sizeof(ushort_t));
        size_t o_qp   = alloc(3 * plane_n * sizeof(ushort_t));
        size_t o_cnt  = alloc(2 * (size_t)n_nodes * sizeof(int));
        size_t o_sort = alloc((size_t)n_edges * sizeof(int));
        size_t o_bsum = alloc(512 * sizeof(int));
        size_t o_flag = alloc(16);
        if (ws_size >= off) {
            ushort_t* sp = (ushort_t*)(ws + o_sp);
            ushort_t* qp = (ushort_t*)(ws + o_qp);
            int* counts = (int*)(ws + o_cnt);
            int* cur = counts + n_nodes;
            int* sorted = (int*)(ws + o_sort);
            int* bsum = (int*)(ws + o_bsum);
            int* bscan = bsum + 256;
            int* flag = (int*)(ws + o_flag);

            hipMemsetAsync(counts, 0, (size_t)n_nodes * sizeof(int), stream);
            hipMemsetAsync(d_out, 0, (size_t)out_size * sizeof(float), stream);
            detect_idx_kernel<<<1, 64, 0, stream>>>(eidx, flag);
            hist_kernel<<<1024, 256, 0, stream>>>(eidx, flag, counts, n_edges);
            scan1_kernel<<<nb, 256, 0, stream>>>(counts, bsum, n_nodes, ch);
            scan2_kernel<<<1, 256, 0, stream>>>(bsum, bscan, nb);
            scan3_kernel<<<nb, 256, 0, stream>>>(counts, bscan, cur, n_nodes, ch);
            scatter_kernel<<<1024, 256, 0, stream>>>(eidx, flag, cur, sorted, n_edges);
            eq_cast_kernel<<<1024, 256, 0, stream>>>(eq, qp, qp + plane_n, qp + 2 * plane_n,
                                                     n_nodes);
            node_mlp3b<<<512, 256, 0, stream>>>(node, Ws, bs, Wphi, bphi,
                                                sp, sp + plane_n, sp + 2 * plane_n, n_nodes);
            const int n_tiles = (n_edges + 63) / 64;
            accum3_kernel<false><<<(n_tiles + 3) / 4, 256, 0, stream>>>(
                sp, sp + plane_n, sp + 2 * plane_n,
                qp, qp + plane_n, qp + 2 * plane_n,
                (const uint4*)nullptr, rbf, env, rij, eidx, flag, sorted,
                Ww, bw, ds, dv, n_edges);
            return;
        }
    }

    // ---- Tier-3: round-1 fallback ----
    {
        float* s_ws = (float*)d_ws;
        int* idx_flag = (int*)(ws + (size_t)n_nodes * 192 * sizeof(float));
        hipMemsetAsync(d_out, 0, (size_t)out_size * sizeof(float), stream);
        detect_idx_kernel<<<1, 64, 0, stream>>>(eidx, idx_flag);
        node_mlp_kernel<<<1024, 256, 0, stream>>>(node, Ws, bs, Wphi, bphi, s_ws, n_nodes);
        edge_kernel<<<4096, 256, 0, stream>>>(s_ws, eq, rbf, env, rij, eidx, idx_flag,
                                              Ww, bw, ds, dv, n_edges);
    }
}